// Round 2
// baseline (1553.204 us; speedup 1.0000x reference)
//
#include <hip/hip_runtime.h>
#include <math.h>

#define NB   4
#define NH   16
#define SLQ  1024
#define SLK  2048
#define DM   1024
#define HD   64

// ---------------------------------------------------------------------------
// fp32 tiled GEMM + bias: C[M,1024] = A[M,1024] @ W[1024,1024] + bias
// 64x64 tile, BK=16, 256 threads, 4x4 per thread. As stored [k][m] (pad 68)
// so compute reads are ds_read_b128, conflict-free / 2-way only.
// ---------------------------------------------------------------------------
__global__ __launch_bounds__(256) void gemm_bias_k(
    const float* __restrict__ A, const float* __restrict__ W,
    const float* __restrict__ bias, float* __restrict__ C) {
  __shared__ float As[16][68];   // [k][m]
  __shared__ float Bs[16][64];   // [k][n]
  const int tid = threadIdx.x;
  const int tx = tid & 15, ty = tid >> 4;
  const int m0 = blockIdx.y * 64, n0 = blockIdx.x * 64;
  const int lr = tid >> 2, lq = tid & 3;   // A loader: row, k-quad
  const int wk = tid >> 4, wn = tid & 15;  // W loader: k-row, n-quad
  float acc[4][4] = {};
  for (int k0 = 0; k0 < DM; k0 += 16) {
    float4 av  = *(const float4*)(A + (size_t)(m0 + lr) * DM + k0 + lq * 4);
    float4 wv4 = *(const float4*)(W + (size_t)(k0 + wk) * DM + n0 + wn * 4);
    As[lq*4+0][lr] = av.x; As[lq*4+1][lr] = av.y;
    As[lq*4+2][lr] = av.z; As[lq*4+3][lr] = av.w;
    *(float4*)&Bs[wk][wn*4] = wv4;
    __syncthreads();
#pragma unroll
    for (int kk = 0; kk < 16; ++kk) {
      float4 a4 = *(const float4*)&As[kk][ty*4];
      float4 b4 = *(const float4*)&Bs[kk][tx*4];
      const float a[4] = {a4.x, a4.y, a4.z, a4.w};
      const float b[4] = {b4.x, b4.y, b4.z, b4.w};
#pragma unroll
      for (int i = 0; i < 4; ++i)
#pragma unroll
        for (int j = 0; j < 4; ++j) acc[i][j] = fmaf(a[i], b[j], acc[i][j]);
    }
    __syncthreads();
  }
  float4 bb = *(const float4*)(bias + n0 + tx*4);
#pragma unroll
  for (int i = 0; i < 4; ++i) {
    float4 o = make_float4(acc[i][0] + bb.x, acc[i][1] + bb.y,
                           acc[i][2] + bb.z, acc[i][3] + bb.w);
    *(float4*)(C + (size_t)(m0 + ty*4 + i) * DM + n0 + tx*4) = o;
  }
}

// ---------------------------------------------------------------------------
// Flash attention per (b, h, 64-row q tile). 256 threads, 4x4 reg blocking.
// qs/ks stored [d][row] (transposed) so the score loop reads float4 of rows;
// vs/ps stored [k][col]. Writes wv (unmerged head slice) and (m,l) per row.
// Loader: 64x64 tile = 1024 float4s -> each of 256 threads loads 4 (c-loop).
// ---------------------------------------------------------------------------
__global__ __launch_bounds__(256) void attn_flash_k(
    const float* __restrict__ q, const float* __restrict__ k,
    const float* __restrict__ v, const int* __restrict__ mask,
    float* __restrict__ wv, float* __restrict__ ml) {
  __shared__ float qs[64][68];   // [d][qr]
  __shared__ float ks[64][68];   // [d][kk]
  __shared__ float vs[64][68];   // [kk][dv]
  __shared__ float ps[64][68];   // [kk][qr]
  const int qt = blockIdx.x, h = blockIdx.y, b = blockIdx.z;
  const int tid = threadIdx.x, tx = tid & 15, ty = tid >> 4;
  const int q0 = qt * 64;
  const int lr = tid >> 2, lq = tid & 3;
#pragma unroll
  for (int c = 0; c < 4; ++c) {
    const int dq = lq + 4*c;   // quad index 0..15
    float4 qv = *(const float4*)(q + (size_t)(b*SLQ + q0 + lr) * DM + h*HD + dq*4);
    qs[dq*4+0][lr] = qv.x; qs[dq*4+1][lr] = qv.y;
    qs[dq*4+2][lr] = qv.z; qs[dq*4+3][lr] = qv.w;
  }
  float O[4][4] = {};
  float m_r[4] = {-INFINITY, -INFINITY, -INFINITY, -INFINITY};
  float l_r[4] = {};
  __syncthreads();
  for (int j0 = 0; j0 < SLK; j0 += 64) {
#pragma unroll
    for (int c = 0; c < 4; ++c) {
      const int dq = lq + 4*c;
      float4 kv = *(const float4*)(k + (size_t)(b*SLK + j0 + lr) * DM + h*HD + dq*4);
      ks[dq*4+0][lr] = kv.x; ks[dq*4+1][lr] = kv.y;
      ks[dq*4+2][lr] = kv.z; ks[dq*4+3][lr] = kv.w;
      float4 vv = *(const float4*)(v + (size_t)(b*SLK + j0 + lr) * DM + h*HD + dq*4);
      *(float4*)&vs[lr][dq*4] = vv;
    }
    __syncthreads();
    // scores s[qr=ty*4+i][kk=tx*4+j]
    float s[4][4] = {};
#pragma unroll 16
    for (int d = 0; d < 64; ++d) {
      float4 a4 = *(const float4*)&qs[d][ty*4];
      float4 b4 = *(const float4*)&ks[d][tx*4];
      const float a[4]  = {a4.x, a4.y, a4.z, a4.w};
      const float bb[4] = {b4.x, b4.y, b4.z, b4.w};
#pragma unroll
      for (int i = 0; i < 4; ++i)
#pragma unroll
        for (int j = 0; j < 4; ++j) s[i][j] = fmaf(a[i], bb[j], s[i][j]);
    }
    // mask + online softmax (row reductions over the 16 tx lanes, in-wave)
#pragma unroll
    for (int i = 0; i < 4; ++i) {
      int4 mv = *(const int4*)(mask + (size_t)(b*SLQ + q0 + ty*4 + i) * SLK + j0 + tx*4);
      s[i][0] = mv.x ? s[i][0]*0.125f : -1e9f;
      s[i][1] = mv.y ? s[i][1]*0.125f : -1e9f;
      s[i][2] = mv.z ? s[i][2]*0.125f : -1e9f;
      s[i][3] = mv.w ? s[i][3]*0.125f : -1e9f;
      float mx = fmaxf(fmaxf(s[i][0], s[i][1]), fmaxf(s[i][2], s[i][3]));
#pragma unroll
      for (int off = 1; off < 16; off <<= 1) mx = fmaxf(mx, __shfl_xor(mx, off, 64));
      float mnew  = fmaxf(m_r[i], mx);
      float alpha = __expf(m_r[i] - mnew);
      m_r[i] = mnew;
      float rs = 0.f;
#pragma unroll
      for (int j = 0; j < 4; ++j) {
        float p = __expf(s[i][j] - mnew);
        s[i][j] = p; rs += p;
      }
#pragma unroll
      for (int off = 1; off < 16; off <<= 1) rs += __shfl_xor(rs, off, 64);
      l_r[i] = l_r[i]*alpha + rs;
#pragma unroll
      for (int j = 0; j < 4; ++j) O[i][j] *= alpha;
#pragma unroll
      for (int j = 0; j < 4; ++j) ps[tx*4+j][ty*4+i] = s[i][j];
    }
    __syncthreads();
    // O[qr][dv] += sum_kk p[kk][qr] * v[kk][dv]
#pragma unroll 16
    for (int kk = 0; kk < 64; ++kk) {
      float4 p4 = *(const float4*)&ps[kk][ty*4];
      float4 v4 = *(const float4*)&vs[kk][tx*4];
      const float p[4]  = {p4.x, p4.y, p4.z, p4.w};
      const float vvv[4] = {v4.x, v4.y, v4.z, v4.w};
#pragma unroll
      for (int i = 0; i < 4; ++i)
#pragma unroll
        for (int j = 0; j < 4; ++j) O[i][j] = fmaf(p[i], vvv[j], O[i][j]);
    }
    __syncthreads();
  }
#pragma unroll
  for (int i = 0; i < 4; ++i) {
    float inv = 1.0f / l_r[i];
    float4 o = make_float4(O[i][0]*inv, O[i][1]*inv, O[i][2]*inv, O[i][3]*inv);
    *(float4*)(wv + (size_t)(b*SLQ + q0 + ty*4 + i) * DM + h*HD + tx*4) = o;
    if (tx == 0) {
      float* mp = ml + ((size_t)(b*NH + h) * SLQ + q0 + ty*4 + i) * 2;
      mp[0] = m_r[i]; mp[1] = l_r[i];
    }
  }
}

// ---------------------------------------------------------------------------
// weight_mean by recomputation: block = (b, 64-row q tile, 256-key tile);
// loops all 16 heads in-block (cross-head sum without atomics), using stored
// (m,l). Mask packed to bits once. w = exp(s/8 - m)/l, masked -> 0.
// ---------------------------------------------------------------------------
__global__ __launch_bounds__(256) void wmean_k(
    const float* __restrict__ q, const float* __restrict__ k,
    const int* __restrict__ mask, const float* __restrict__ ml,
    float* __restrict__ wm_out) {
  __shared__ float qs[64][68];   // [d][qr]
  __shared__ float ks[64][68];   // [d][kk]
  const int jt = blockIdx.x, qt = blockIdx.y, b = blockIdx.z;
  const int tid = threadIdx.x, tx = tid & 15, ty = tid >> 4;
  const int q0 = qt * 64, j0 = jt * 256;
  const int lr = tid >> 2, lq = tid & 3;
  unsigned mbits[4];
#pragma unroll
  for (int i = 0; i < 4; ++i) {
    unsigned bits = 0;
#pragma unroll
    for (int js = 0; js < 4; ++js) {
      int4 mv = *(const int4*)(mask + (size_t)(b*SLQ + q0 + ty*4 + i) * SLK + j0 + js*64 + tx*4);
      bits |= (mv.x ? 1u : 0u) << (js*4+0);
      bits |= (mv.y ? 1u : 0u) << (js*4+1);
      bits |= (mv.z ? 1u : 0u) << (js*4+2);
      bits |= (mv.w ? 1u : 0u) << (js*4+3);
    }
    mbits[i] = bits;
  }
  float wm[4][16] = {};
  for (int h = 0; h < NH; ++h) {
    __syncthreads();   // previous-h reads of qs done
#pragma unroll
    for (int c = 0; c < 4; ++c) {
      const int dq = lq + 4*c;
      float4 qv = *(const float4*)(q + (size_t)(b*SLQ + q0 + lr) * DM + h*HD + dq*4);
      qs[dq*4+0][lr] = qv.x; qs[dq*4+1][lr] = qv.y;
      qs[dq*4+2][lr] = qv.z; qs[dq*4+3][lr] = qv.w;
    }
    float mrow[4], linv[4];
#pragma unroll
    for (int i = 0; i < 4; ++i) {
      const float* mp = ml + ((size_t)(b*NH + h) * SLQ + q0 + ty*4 + i) * 2;
      mrow[i] = mp[0]; linv[i] = 1.0f / mp[1];
    }
    for (int js = 0; js < 4; ++js) {
      __syncthreads();  // qs staged / previous ks reads done
#pragma unroll
      for (int c = 0; c < 4; ++c) {
        const int dq = lq + 4*c;
        float4 kv = *(const float4*)(k + (size_t)(b*SLK + j0 + js*64 + lr) * DM + h*HD + dq*4);
        ks[dq*4+0][lr] = kv.x; ks[dq*4+1][lr] = kv.y;
        ks[dq*4+2][lr] = kv.z; ks[dq*4+3][lr] = kv.w;
      }
      __syncthreads();
      float s[4][4] = {};
#pragma unroll 16
      for (int d = 0; d < 64; ++d) {
        float4 a4 = *(const float4*)&qs[d][ty*4];
        float4 b4 = *(const float4*)&ks[d][tx*4];
        const float a[4]  = {a4.x, a4.y, a4.z, a4.w};
        const float bb[4] = {b4.x, b4.y, b4.z, b4.w};
#pragma unroll
        for (int i = 0; i < 4; ++i)
#pragma unroll
          for (int j = 0; j < 4; ++j) s[i][j] = fmaf(a[i], bb[j], s[i][j]);
      }
#pragma unroll
      for (int i = 0; i < 4; ++i)
#pragma unroll
        for (int jj = 0; jj < 4; ++jj) {
          float w = ((mbits[i] >> (js*4+jj)) & 1u)
                      ? __expf(s[i][jj]*0.125f - mrow[i]) * linv[i] : 0.f;
          wm[i][js*4+jj] += w;
        }
    }
  }
#pragma unroll
  for (int i = 0; i < 4; ++i)
#pragma unroll
    for (int js = 0; js < 4; ++js) {
      float4 o = make_float4(wm[i][js*4+0]*0.0625f, wm[i][js*4+1]*0.0625f,
                             wm[i][js*4+2]*0.0625f, wm[i][js*4+3]*0.0625f);
      *(float4*)(wm_out + (size_t)(b*SLQ + q0 + ty*4 + i) * SLK + j0 + js*64 + tx*4) = o;
    }
}

// ---------------------------------------------------------------------------
extern "C" void kernel_launch(void* const* d_in, const int* in_sizes, int n_in,
                              void* d_out, int out_size, void* d_ws, size_t ws_size,
                              hipStream_t stream) {
  const float* mq    = (const float*)d_in[0];
  const float* reply = (const float*)d_in[1];
  const int*   maskp = (const int*)  d_in[2];
  const float* Wq = (const float*)d_in[3];
  const float* bq = (const float*)d_in[4];
  const float* Wk = (const float*)d_in[5];
  const float* bk = (const float*)d_in[6];
  const float* Wv = (const float*)d_in[7];
  const float* bv = (const float*)d_in[8];
  const float* Wo = (const float*)d_in[9];
  const float* bo = (const float*)d_in[10];

  float* out0 = (float*)d_out;                       // [4,1024,1024]
  float* out1 = out0 + (size_t)NB*SLQ*DM;            // weight_mean [4,1024,2048]

  // workspace layout (fp32), total ~96.5 MB
  float* qb  = (float*)d_ws;
  float* kb  = qb  + (size_t)NB*SLQ*DM;
  float* vb  = kb  + (size_t)NB*SLK*DM;
  float* wvb = vb  + (size_t)NB*SLK*DM;
  float* mlb = wvb + (size_t)NB*SLQ*DM;

  // projections
  gemm_bias_k<<<dim3(DM/64, (NB*SLQ)/64), 256, 0, stream>>>(mq,    Wq, bq, qb);
  gemm_bias_k<<<dim3(DM/64, (NB*SLK)/64), 256, 0, stream>>>(reply, Wk, bk, kb);
  gemm_bias_k<<<dim3(DM/64, (NB*SLK)/64), 256, 0, stream>>>(reply, Wv, bv, vb);
  // flash attention -> wv, (m,l)
  attn_flash_k<<<dim3(SLQ/64, NH, NB), 256, 0, stream>>>(qb, kb, vb, maskp, wvb, mlb);
  // weight_mean by recomputation
  wmean_k<<<dim3(SLK/256, SLQ/64, NB), 256, 0, stream>>>(qb, kb, maskp, mlb, out1);
  // output projection
  gemm_bias_k<<<dim3(DM/64, (NB*SLQ)/64), 256, 0, stream>>>(wvb, Wo, bo, out0);
}

// Round 3
// 532.952 us; speedup vs baseline: 2.9143x; 2.9143x over previous
//
#include <hip/hip_runtime.h>
#include <math.h>

#define NB   4
#define NH   16
#define SLQ  1024
#define SLK  2048
#define DM   1024
#define HD   64

typedef __attribute__((ext_vector_type(8))) short s16x8;
typedef __attribute__((ext_vector_type(4))) short s16x4;
typedef __attribute__((ext_vector_type(4))) float f32x4;
typedef unsigned short u16;
typedef unsigned int   u32;

__device__ inline u16 f2bf(float f) {
  u32 u = __float_as_uint(f);
  u32 r = u + 0x7fffu + ((u >> 16) & 1u);
  return (u16)(r >> 16);
}
__device__ inline float bf2f(u16 h) { return __uint_as_float(((u32)h) << 16); }

// ---------------------------------------------------------------------------
// mask -> bitmask (1 bit per (q,key)); wave ballot, 64 keys per wave-iter.
// ---------------------------------------------------------------------------
__global__ __launch_bounds__(256) void maskbits_k(
    const int* __restrict__ mask, unsigned long long* __restrict__ bits, int nwords) {
  int gw   = (blockIdx.x * blockDim.x + threadIdx.x) >> 6;
  int lane = threadIdx.x & 63;
  int nw   = (gridDim.x * blockDim.x) >> 6;
  for (int w = gw; w < nwords; w += nw) {
    int m = mask[(size_t)w * 64 + lane];
    unsigned long long b = __ballot(m != 0);
    if (lane == 0) bits[w] = b;
  }
}

// ---------------------------------------------------------------------------
// W[1024][1024] f32 -> WT_hi/lo [n][k] bf16 (transposed + hi/lo split).
// ---------------------------------------------------------------------------
__global__ __launch_bounds__(256) void splitT_k(
    const float* __restrict__ W, u16* __restrict__ Thi, u16* __restrict__ Tlo) {
  __shared__ float ts[64][68];
  const int t = threadIdx.x;
  const int r0 = blockIdx.y * 64, c0 = blockIdx.x * 64;
  const int rr = t >> 4, cc = t & 15;
#pragma unroll
  for (int p = 0; p < 4; ++p) {
    float4 v = *(const float4*)(W + (size_t)(r0 + rr + p*16) * DM + c0 + cc*4);
    *(float4*)&ts[rr + p*16][cc*4] = v;
  }
  __syncthreads();
  const int c = t >> 2, ch = t & 3;
  s16x8 h0, h1, l0, l1;
#pragma unroll
  for (int i = 0; i < 8; ++i) {
    float a = ts[ch*16 + i][c];
    u16 h = f2bf(a); h0[i] = (short)h; l0[i] = (short)f2bf(a - bf2f(h));
    float b = ts[ch*16 + 8 + i][c];
    u16 h2 = f2bf(b); h1[i] = (short)h2; l1[i] = (short)f2bf(b - bf2f(h2));
  }
  size_t base = (size_t)(c0 + c) * DM + r0 + ch*16;
  *(s16x8*)(Thi + base) = h0; *(s16x8*)(Thi + base + 8) = h1;
  *(s16x8*)(Tlo + base) = l0; *(s16x8*)(Tlo + base + 8) = l1;
}

// ---------------------------------------------------------------------------
// MFMA GEMM: C[M,1024] = A[M,1024] @ W + bias, via 16x16x32 bf16.
// 128x128 tile, BK=32, 4 waves (2x2), 4x4 frags/wave.
// A_MODE: 0 = f32 global, split staging (hi+lo); 1 = f32, plain (hi only);
//         2 = pre-split bf16 (Aptr=hi, Alo_ptr=lo).
// OUT_MODE: 0 = bf16 hi/lo natural [M][1024]; 1 = bf16 plain, transposed
//           vT [b][h][dv][SLK]; 2 = f32 natural.
// SPLIT compute (3 MFMA) when A_MODE != 1.
// ---------------------------------------------------------------------------
template<int A_MODE, int OUT_MODE>
__global__ __launch_bounds__(256) void gemm_mfma(
    const void* __restrict__ Aptr, const void* __restrict__ Alo_ptr,
    const u16* __restrict__ BThi, const u16* __restrict__ BTlo,
    const float* __restrict__ bias,
    void* __restrict__ Out0, void* __restrict__ Out1) {
  constexpr bool SPLIT = (A_MODE != 1);
  __shared__ u16 Ah[128][40];
  __shared__ u16 Bh[128][40];
  __shared__ u16 Al[SPLIT ? 128 : 1][40];
  __shared__ u16 Bl[SPLIT ? 128 : 1][40];
  const int t = threadIdx.x;
  const int m0 = blockIdx.y * 128, n0 = blockIdx.x * 128;
  const int wid = t >> 6, lane = t & 63, lg = lane >> 4, lm = lane & 15;
  const int wr = wid >> 1, wc = wid & 1;
  f32x4 acc[4][4];
#pragma unroll
  for (int i = 0; i < 4; ++i)
#pragma unroll
    for (int j = 0; j < 4; ++j) acc[i][j] = (f32x4)(0.0f);

  const int row = t >> 1, half = t & 1;
  for (int k0 = 0; k0 < DM; k0 += 32) {
    // ---- stage A ----
    if (A_MODE == 0 || A_MODE == 1) {
      const float* A = (const float*)Aptr;
      const float* src = A + (size_t)(m0 + row) * DM + k0 + half * 16;
      float vv[16];
      *(float4*)&vv[0]  = *(const float4*)(src + 0);
      *(float4*)&vv[4]  = *(const float4*)(src + 4);
      *(float4*)&vv[8]  = *(const float4*)(src + 8);
      *(float4*)&vv[12] = *(const float4*)(src + 12);
      s16x8 h0, h1, l0, l1;
#pragma unroll
      for (int i = 0; i < 8; ++i) {
        u16 ha = f2bf(vv[i]);     h0[i] = (short)ha;
        u16 hb = f2bf(vv[8 + i]); h1[i] = (short)hb;
        if constexpr (SPLIT) {
          l0[i] = (short)f2bf(vv[i]     - bf2f(ha));
          l1[i] = (short)f2bf(vv[8 + i] - bf2f(hb));
        }
      }
      *(s16x8*)&Ah[row][half*16]     = h0;
      *(s16x8*)&Ah[row][half*16 + 8] = h1;
      if constexpr (SPLIT) {
        *(s16x8*)&Al[row][half*16]     = l0;
        *(s16x8*)&Al[row][half*16 + 8] = l1;
      }
    } else {
      const u16* Ahg = (const u16*)Aptr;
      const u16* Alg = (const u16*)Alo_ptr;
      size_t aoff = (size_t)(m0 + row) * DM + k0 + half * 16;
      *(s16x8*)&Ah[row][half*16]     = *(const s16x8*)(Ahg + aoff);
      *(s16x8*)&Ah[row][half*16 + 8] = *(const s16x8*)(Ahg + aoff + 8);
      *(s16x8*)&Al[row][half*16]     = *(const s16x8*)(Alg + aoff);
      *(s16x8*)&Al[row][half*16 + 8] = *(const s16x8*)(Alg + aoff + 8);
    }
    // ---- stage B (always pre-split bf16 WT[n][k]) ----
    {
      size_t boff = (size_t)(n0 + row) * DM + k0 + half * 16;
      *(s16x8*)&Bh[row][half*16]     = *(const s16x8*)(BThi + boff);
      *(s16x8*)&Bh[row][half*16 + 8] = *(const s16x8*)(BThi + boff + 8);
      if constexpr (SPLIT) {
        *(s16x8*)&Bl[row][half*16]     = *(const s16x8*)(BTlo + boff);
        *(s16x8*)&Bl[row][half*16 + 8] = *(const s16x8*)(BTlo + boff + 8);
      }
    }
    __syncthreads();
    s16x8 ah[4], al[4], bh[4], bl[4];
#pragma unroll
    for (int i = 0; i < 4; ++i) {
      ah[i] = *(const s16x8*)&Ah[wr*64 + i*16 + lm][lg*8];
      bh[i] = *(const s16x8*)&Bh[wc*64 + i*16 + lm][lg*8];
      if constexpr (SPLIT) {
        al[i] = *(const s16x8*)&Al[wr*64 + i*16 + lm][lg*8];
        bl[i] = *(const s16x8*)&Bl[wc*64 + i*16 + lm][lg*8];
      }
    }
#pragma unroll
    for (int i = 0; i < 4; ++i)
#pragma unroll
      for (int j = 0; j < 4; ++j) {
        acc[i][j] = __builtin_amdgcn_mfma_f32_16x16x32_bf16(ah[i], bh[j], acc[i][j], 0, 0, 0);
        if constexpr (SPLIT) {
          acc[i][j] = __builtin_amdgcn_mfma_f32_16x16x32_bf16(ah[i], bl[j], acc[i][j], 0, 0, 0);
          acc[i][j] = __builtin_amdgcn_mfma_f32_16x16x32_bf16(al[i], bh[j], acc[i][j], 0, 0, 0);
        }
      }
    __syncthreads();
  }
  // ---- epilogue ----
#pragma unroll
  for (int i = 0; i < 4; ++i)
#pragma unroll
    for (int j = 0; j < 4; ++j) {
      const int colg = n0 + wc*64 + j*16 + lm;
      const int rowb = m0 + wr*64 + i*16 + lg*4;
      const float bcol = bias[colg];
      if constexpr (OUT_MODE == 2) {
        float* O = (float*)Out0;
#pragma unroll
        for (int r = 0; r < 4; ++r)
          O[(size_t)(rowb + r) * DM + colg] = acc[i][j][r] + bcol;
      } else if constexpr (OUT_MODE == 0) {
        u16* Oh = (u16*)Out0; u16* Ol = (u16*)Out1;
#pragma unroll
        for (int r = 0; r < 4; ++r) {
          float v = acc[i][j][r] + bcol;
          u16 h = f2bf(v);
          Oh[(size_t)(rowb + r) * DM + colg] = h;
          Ol[(size_t)(rowb + r) * DM + colg] = f2bf(v - bf2f(h));
        }
      } else {  // vT transposed, plain bf16
        u16* OT = (u16*)Out0;
        const int bb = rowb >> 11, key = rowb & 2047;
        const int hh = colg >> 6, dv = colg & 63;
        s16x4 pk;
#pragma unroll
        for (int r = 0; r < 4; ++r) pk[r] = (short)f2bf(acc[i][j][r] + bcol);
        *(s16x4*)((u16*)OT + (((size_t)bb*NH + hh)*HD + dv)*SLK + key) = pk;
      }
    }
}

// ---------------------------------------------------------------------------
// Flash attention, MFMA. Block = (qt64, h, b), 4 waves; wave owns 16 q rows.
// QK^T split (3x), PV plain. Writes wv hi/lo + (m,l).
// ---------------------------------------------------------------------------
__global__ __launch_bounds__(256) void attn_mfma_k(
    const u16* __restrict__ qhi, const u16* __restrict__ qlo,
    const u16* __restrict__ khi, const u16* __restrict__ klo,
    const u16* __restrict__ vT,  const u32* __restrict__ mbits,
    u16* __restrict__ wvhi, u16* __restrict__ wvlo, float* __restrict__ ml) {
  __shared__ u16 ks_h[64][72];
  __shared__ u16 ks_l[64][72];
  __shared__ u16 vs[64][72];
  __shared__ u16 ps[4][16][72];
  const int qt = blockIdx.x, h = blockIdx.y, b = blockIdx.z;
  const int t = threadIdx.x, wid = t >> 6, lane = t & 63, lg = lane >> 4, lm = lane & 15;
  const int q0 = qt * 64, qw = q0 + wid * 16;
  s16x8 qh[2], ql[2];
#pragma unroll
  for (int s = 0; s < 2; ++s) {
    size_t off = ((size_t)(b*SLQ + qw + lm)) * DM + h*HD + s*32 + lg*8;
    qh[s] = *(const s16x8*)(qhi + off);
    ql[s] = *(const s16x8*)(qlo + off);
  }
  f32x4 O[4];
#pragma unroll
  for (int j = 0; j < 4; ++j) O[j] = (f32x4)(0.0f);
  float m_r[4] = {-INFINITY, -INFINITY, -INFINITY, -INFINITY};
  float l_r[4] = {0.f, 0.f, 0.f, 0.f};
  const int srow = t >> 2, sch = t & 3;
  for (int j0 = 0; j0 < SLK; j0 += 64) {
    {
      size_t koff = ((size_t)(b*SLK + j0 + srow)) * DM + h*HD + sch*16;
      *(s16x8*)&ks_h[srow][sch*16]     = *(const s16x8*)(khi + koff);
      *(s16x8*)&ks_h[srow][sch*16 + 8] = *(const s16x8*)(khi + koff + 8);
      *(s16x8*)&ks_l[srow][sch*16]     = *(const s16x8*)(klo + koff);
      *(s16x8*)&ks_l[srow][sch*16 + 8] = *(const s16x8*)(klo + koff + 8);
      size_t voff = (((size_t)b*NH + h)*HD + srow)*SLK + j0 + sch*16;
      *(s16x8*)&vs[srow][sch*16]     = *(const s16x8*)(vT + voff);
      *(s16x8*)&vs[srow][sch*16 + 8] = *(const s16x8*)(vT + voff + 8);
    }
    __syncthreads();
    // QK^T (split)
    f32x4 sc[4];
#pragma unroll
    for (int j = 0; j < 4; ++j) {
      s16x8 kh0 = *(const s16x8*)&ks_h[j*16 + lm][lg*8];
      s16x8 kh1 = *(const s16x8*)&ks_h[j*16 + lm][32 + lg*8];
      s16x8 kl0 = *(const s16x8*)&ks_l[j*16 + lm][lg*8];
      s16x8 kl1 = *(const s16x8*)&ks_l[j*16 + lm][32 + lg*8];
      f32x4 c = (f32x4)(0.0f);
      c = __builtin_amdgcn_mfma_f32_16x16x32_bf16(qh[0], kh0, c, 0, 0, 0);
      c = __builtin_amdgcn_mfma_f32_16x16x32_bf16(qh[1], kh1, c, 0, 0, 0);
      c = __builtin_amdgcn_mfma_f32_16x16x32_bf16(qh[0], kl0, c, 0, 0, 0);
      c = __builtin_amdgcn_mfma_f32_16x16x32_bf16(qh[1], kl1, c, 0, 0, 0);
      c = __builtin_amdgcn_mfma_f32_16x16x32_bf16(ql[0], kh0, c, 0, 0, 0);
      c = __builtin_amdgcn_mfma_f32_16x16x32_bf16(ql[1], kh1, c, 0, 0, 0);
      sc[j] = c;
    }
    // mask + online softmax per q-row (reg r)
#pragma unroll
    for (int r = 0; r < 4; ++r) {
      size_t mrow = ((size_t)(b*SLQ + qw + lg*4 + r)) * (SLK/32) + (j0 >> 5);
      u32 w0 = mbits[mrow], w1 = mbits[mrow + 1];
      float sv[4];
#pragma unroll
      for (int j = 0; j < 4; ++j) {
        u32 w = (j < 2) ? w0 : w1;
        int bit = (w >> ((j*16 + lm) & 31)) & 1;
        sv[j] = bit ? sc[j][r] * 0.125f : -1e9f;
      }
      float mx = fmaxf(fmaxf(sv[0], sv[1]), fmaxf(sv[2], sv[3]));
#pragma unroll
      for (int off = 1; off < 16; off <<= 1) mx = fmaxf(mx, __shfl_xor(mx, off, 64));
      float mnew  = fmaxf(m_r[r], mx);
      float alpha = __expf(m_r[r] - mnew);
      m_r[r] = mnew;
      float rs = 0.f;
      float p[4];
#pragma unroll
      for (int j = 0; j < 4; ++j) { p[j] = __expf(sv[j] - mnew); rs += p[j]; }
#pragma unroll
      for (int off = 1; off < 16; off <<= 1) rs += __shfl_xor(rs, off, 64);
      l_r[r] = l_r[r] * alpha + rs;
#pragma unroll
      for (int j = 0; j < 4; ++j) O[j][r] *= alpha;
#pragma unroll
      for (int j = 0; j < 4; ++j) ps[wid][lg*4 + r][j*16 + lm] = f2bf(p[j]);
    }
    // PV (plain)
    {
      s16x8 pa0 = *(const s16x8*)&ps[wid][lm][lg*8];
      s16x8 pa1 = *(const s16x8*)&ps[wid][lm][32 + lg*8];
#pragma unroll
      for (int j = 0; j < 4; ++j) {
        s16x8 vb0 = *(const s16x8*)&vs[j*16 + lm][lg*8];
        s16x8 vb1 = *(const s16x8*)&vs[j*16 + lm][32 + lg*8];
        O[j] = __builtin_amdgcn_mfma_f32_16x16x32_bf16(pa0, vb0, O[j], 0, 0, 0);
        O[j] = __builtin_amdgcn_mfma_f32_16x16x32_bf16(pa1, vb1, O[j], 0, 0, 0);
      }
    }
    __syncthreads();
  }
#pragma unroll
  for (int j = 0; j < 4; ++j)
#pragma unroll
    for (int r = 0; r < 4; ++r) {
      float v = O[j][r] / l_r[r];
      size_t row = (size_t)(b*SLQ + qw + lg*4 + r);
      int col = h*HD + j*16 + lm;
      u16 hh = f2bf(v);
      wvhi[row*DM + col] = hh;
      wvlo[row*DM + col] = f2bf(v - bf2f(hh));
    }
  if (lm == 0) {
#pragma unroll
    for (int r = 0; r < 4; ++r) {
      float* mp = ml + ((size_t)(b*NH + h)*SLQ + qw + lg*4 + r) * 2;
      mp[0] = m_r[r]; mp[1] = l_r[r];
    }
  }
}

// ---------------------------------------------------------------------------
// weight_mean: block = (jt-group of 4 x 64 keys, qt64, b); loop h in-block.
// QK^T plain bf16 (hi only); w = exp(s/8 - m)/l, masked -> 0; mean over h.
// ---------------------------------------------------------------------------
__global__ __launch_bounds__(256) void wmean_mfma_k(
    const u16* __restrict__ qhi, const u16* __restrict__ khi,
    const u32* __restrict__ mbits, const float* __restrict__ ml,
    float* __restrict__ out1) {
  __shared__ u16 ks[64][72];
  const int t = threadIdx.x, wid = t >> 6, lane = t & 63, lg = lane >> 4, lm = lane & 15;
  const int q0 = blockIdx.y * 64, b = blockIdx.z, qw = q0 + wid * 16;
  const int srow = t >> 2, sch = t & 3;
  for (int jt = 0; jt < 4; ++jt) {
    const int j0 = blockIdx.x * 256 + jt * 64;
    f32x4 wm[4];
#pragma unroll
    for (int j = 0; j < 4; ++j) wm[j] = (f32x4)(0.0f);
    u32 w0[4], w1[4];
#pragma unroll
    for (int r = 0; r < 4; ++r) {
      size_t mrow = ((size_t)(b*SLQ + qw + lg*4 + r)) * (SLK/32) + (j0 >> 5);
      w0[r] = mbits[mrow]; w1[r] = mbits[mrow + 1];
    }
    for (int h = 0; h < NH; ++h) {
      __syncthreads();
      {
        size_t koff = ((size_t)(b*SLK + j0 + srow)) * DM + h*HD + sch*16;
        *(s16x8*)&ks[srow][sch*16]     = *(const s16x8*)(khi + koff);
        *(s16x8*)&ks[srow][sch*16 + 8] = *(const s16x8*)(khi + koff + 8);
      }
      __syncthreads();
      s16x8 qh0, qh1;
      {
        size_t off = ((size_t)(b*SLQ + qw + lm)) * DM + h*HD + lg*8;
        qh0 = *(const s16x8*)(qhi + off);
        qh1 = *(const s16x8*)(qhi + off + 32);
      }
      float mr[4], li[4];
#pragma unroll
      for (int r = 0; r < 4; ++r) {
        const float* mp = ml + ((size_t)(b*NH + h)*SLQ + qw + lg*4 + r) * 2;
        mr[r] = mp[0]; li[r] = 1.0f / mp[1];
      }
#pragma unroll
      for (int j = 0; j < 4; ++j) {
        s16x8 kh0 = *(const s16x8*)&ks[j*16 + lm][lg*8];
        s16x8 kh1 = *(const s16x8*)&ks[j*16 + lm][32 + lg*8];
        f32x4 c = (f32x4)(0.0f);
        c = __builtin_amdgcn_mfma_f32_16x16x32_bf16(qh0, kh0, c, 0, 0, 0);
        c = __builtin_amdgcn_mfma_f32_16x16x32_bf16(qh1, kh1, c, 0, 0, 0);
#pragma unroll
        for (int r = 0; r < 4; ++r) {
          u32 w = (j < 2) ? w0[r] : w1[r];
          int bit = (w >> ((j*16 + lm) & 31)) & 1;
          float wv = bit ? __expf(c[r] * 0.125f - mr[r]) * li[r] : 0.f;
          wm[j][r] += wv;
        }
      }
    }
#pragma unroll
    for (int j = 0; j < 4; ++j)
#pragma unroll
      for (int r = 0; r < 4; ++r)
        out1[((size_t)b*SLQ + q0 + wid*16 + lg*4 + r) * SLK + j0 + j*16 + lm]
            = wm[j][r] * (1.0f / NH);
  }
}

// ---------------------------------------------------------------------------
extern "C" void kernel_launch(void* const* d_in, const int* in_sizes, int n_in,
                              void* d_out, int out_size, void* d_ws, size_t ws_size,
                              hipStream_t stream) {
  const float* mq    = (const float*)d_in[0];
  const float* reply = (const float*)d_in[1];
  const int*   maskp = (const int*)  d_in[2];
  const float* Wq = (const float*)d_in[3];
  const float* bq = (const float*)d_in[4];
  const float* Wk = (const float*)d_in[5];
  const float* bk = (const float*)d_in[6];
  const float* Wv = (const float*)d_in[7];
  const float* bv = (const float*)d_in[8];
  const float* Wo = (const float*)d_in[9];
  const float* bo = (const float*)d_in[10];

  float* out0 = (float*)d_out;
  float* out1 = out0 + (size_t)NB*SLQ*DM;

  // workspace carve (u16 unless noted) -- total ~97.5 MB
  char* w = (char*)d_ws;
  auto carve = [&](size_t bytes) { char* p = w; w += bytes; return p; };
  u16* WqThi = (u16*)carve((size_t)DM*DM*2); u16* WqTlo = (u16*)carve((size_t)DM*DM*2);
  u16* WkThi = (u16*)carve((size_t)DM*DM*2); u16* WkTlo = (u16*)carve((size_t)DM*DM*2);
  u16* WvThi = (u16*)carve((size_t)DM*DM*2); u16* WvTlo = (u16*)carve((size_t)DM*DM*2);
  u16* WoThi = (u16*)carve((size_t)DM*DM*2); u16* WoTlo = (u16*)carve((size_t)DM*DM*2);
  u16* q_hi  = (u16*)carve((size_t)NB*SLQ*DM*2); u16* q_lo = (u16*)carve((size_t)NB*SLQ*DM*2);
  u16* k_hi  = (u16*)carve((size_t)NB*SLK*DM*2); u16* k_lo = (u16*)carve((size_t)NB*SLK*DM*2);
  u16* vT    = (u16*)carve((size_t)NB*SLK*DM*2);
  u16* wv_hi = (u16*)carve((size_t)NB*SLQ*DM*2); u16* wv_lo = (u16*)carve((size_t)NB*SLQ*DM*2);
  float* mlb = (float*)carve((size_t)NB*NH*SLQ*2*4);
  unsigned long long* mbits = (unsigned long long*)carve((size_t)NB*SLQ*SLK/8);

  maskbits_k<<<256, 256, 0, stream>>>(maskp, mbits, NB*SLQ*SLK/64);
  dim3 tg(16, 16);
  splitT_k<<<tg, 256, 0, stream>>>(Wq, WqThi, WqTlo);
  splitT_k<<<tg, 256, 0, stream>>>(Wk, WkThi, WkTlo);
  splitT_k<<<tg, 256, 0, stream>>>(Wv, WvThi, WvTlo);
  splitT_k<<<tg, 256, 0, stream>>>(Wo, WoThi, WoTlo);

  gemm_mfma<0,0><<<dim3(DM/128, (NB*SLQ)/128), 256, 0, stream>>>(
      mq, nullptr, WqThi, WqTlo, bq, q_hi, q_lo);
  gemm_mfma<0,0><<<dim3(DM/128, (NB*SLK)/128), 256, 0, stream>>>(
      reply, nullptr, WkThi, WkTlo, bk, k_hi, k_lo);
  gemm_mfma<1,1><<<dim3(DM/128, (NB*SLK)/128), 256, 0, stream>>>(
      reply, nullptr, WvThi, nullptr, bv, vT, nullptr);

  attn_mfma_k<<<dim3(SLQ/64, NH, NB), 256, 0, stream>>>(
      q_hi, q_lo, k_hi, k_lo, vT, (const u32*)mbits, wv_hi, wv_lo, mlb);

  wmean_mfma_k<<<dim3(SLK/256, SLQ/64, NB), 256, 0, stream>>>(
      q_hi, k_hi, (const u32*)mbits, mlb, out1);

  gemm_mfma<2,2><<<dim3(DM/128, (NB*SLQ)/128), 256, 0, stream>>>(
      wv_hi, wv_lo, WoThi, WoTlo, bo, out0, nullptr);
}

// Round 5
// 417.077 us; speedup vs baseline: 3.7240x; 1.2778x over previous
//
#include <hip/hip_runtime.h>
#include <math.h>

#define NB   4
#define NH   16
#define SLQ  1024
#define SLK  2048
#define DM   1024
#define HD   64

typedef __attribute__((ext_vector_type(8))) short s16x8;
typedef __attribute__((ext_vector_type(4))) short s16x4;
typedef __attribute__((ext_vector_type(4))) float f32x4;
typedef unsigned short u16;
typedef unsigned int   u32;

__device__ inline u16 f2bf(float f) {
  u32 u = __float_as_uint(f);
  u32 r = u + 0x7fffu + ((u >> 16) & 1u);
  return (u16)(r >> 16);
}
__device__ inline float bf2f(u16 h) { return __uint_as_float(((u32)h) << 16); }

// ---------------------------------------------------------------------------
// f32 -> bf16 (plain), vectorized 8/thread, grid-stride.
// ---------------------------------------------------------------------------
__global__ __launch_bounds__(256) void cvt_bf16_k(
    const float* __restrict__ src, u16* __restrict__ dst, int n) {
  int stride = gridDim.x * blockDim.x * 8;
  for (int i = (blockIdx.x * blockDim.x + threadIdx.x) * 8; i < n; i += stride) {
    float4 a = *(const float4*)(src + i);
    float4 b = *(const float4*)(src + i + 4);
    s16x8 o;
    o[0] = (short)f2bf(a.x); o[1] = (short)f2bf(a.y);
    o[2] = (short)f2bf(a.z); o[3] = (short)f2bf(a.w);
    o[4] = (short)f2bf(b.x); o[5] = (short)f2bf(b.y);
    o[6] = (short)f2bf(b.z); o[7] = (short)f2bf(b.w);
    *(s16x8*)(dst + i) = o;
  }
}

// ---------------------------------------------------------------------------
// mask -> bitmask (1 bit per (q,key)); wave ballot, 64 keys per wave-iter.
// ---------------------------------------------------------------------------
__global__ __launch_bounds__(256) void maskbits_k(
    const int* __restrict__ mask, unsigned long long* __restrict__ bits, int nwords) {
  int gw   = (blockIdx.x * blockDim.x + threadIdx.x) >> 6;
  int lane = threadIdx.x & 63;
  int nw   = (gridDim.x * blockDim.x) >> 6;
  for (int w = gw; w < nwords; w += nw) {
    int m = mask[(size_t)w * 64 + lane];
    unsigned long long b = __ballot(m != 0);
    if (lane == 0) bits[w] = b;
  }
}

// ---------------------------------------------------------------------------
// W[1024][1024] f32 -> WT [n][k] bf16 (transposed, plain).
// ---------------------------------------------------------------------------
__global__ __launch_bounds__(256) void convT_k(
    const float* __restrict__ W, u16* __restrict__ T) {
  __shared__ float ts[64][68];
  const int t = threadIdx.x;
  const int r0 = blockIdx.y * 64, c0 = blockIdx.x * 64;
  const int rr = t >> 4, cc = t & 15;
#pragma unroll
  for (int p = 0; p < 4; ++p) {
    float4 v = *(const float4*)(W + (size_t)(r0 + rr + p*16) * DM + c0 + cc*4);
    *(float4*)&ts[rr + p*16][cc*4] = v;
  }
  __syncthreads();
  const int c = t >> 2, ch = t & 3;
  s16x8 h0, h1;
#pragma unroll
  for (int i = 0; i < 8; ++i) {
    h0[i] = (short)f2bf(ts[ch*16 + i][c]);
    h1[i] = (short)f2bf(ts[ch*16 + 8 + i][c]);
  }
  size_t base = (size_t)(c0 + c) * DM + r0 + ch*16;
  *(s16x8*)(T + base) = h0; *(s16x8*)(T + base + 8) = h1;
}

// ---------------------------------------------------------------------------
// bf16 MFMA GEMM: C[M,1024] = A[M,1024] @ W + bias.  A bf16 [M][1024],
// BT bf16 [n][k].  128x128 tile, BK=32, 4 waves (2x2), 4x4 frags/wave.
// OUT_MODE: 0 = bf16 natural; 1 = bf16 transposed vT [b][h][dv][SLK];
//           2 = f32 natural.
// ---------------------------------------------------------------------------
template<int OUT_MODE>
__global__ __launch_bounds__(256) void gemm_bf16_k(
    const u16* __restrict__ Ab, const u16* __restrict__ BT,
    const float* __restrict__ bias, void* __restrict__ Out) {
  __shared__ u16 Ah[128][40];
  __shared__ u16 Bh[128][40];
  const int t = threadIdx.x;
  const int m0 = blockIdx.y * 128, n0 = blockIdx.x * 128;
  const int wid = t >> 6, lane = t & 63, lg = lane >> 4, lm = lane & 15;
  const int wr = wid >> 1, wc = wid & 1;
  f32x4 acc[4][4];
#pragma unroll
  for (int i = 0; i < 4; ++i)
#pragma unroll
    for (int j = 0; j < 4; ++j) acc[i][j] = (f32x4)(0.0f);

  const int row = t >> 1, half = t & 1;
  for (int k0 = 0; k0 < DM; k0 += 32) {
    {
      size_t aoff = (size_t)(m0 + row) * DM + k0 + half * 16;
      *(s16x8*)&Ah[row][half*16]     = *(const s16x8*)(Ab + aoff);
      *(s16x8*)&Ah[row][half*16 + 8] = *(const s16x8*)(Ab + aoff + 8);
      size_t boff = (size_t)(n0 + row) * DM + k0 + half * 16;
      *(s16x8*)&Bh[row][half*16]     = *(const s16x8*)(BT + boff);
      *(s16x8*)&Bh[row][half*16 + 8] = *(const s16x8*)(BT + boff + 8);
    }
    __syncthreads();
    s16x8 ah[4], bh[4];
#pragma unroll
    for (int i = 0; i < 4; ++i) {
      ah[i] = *(const s16x8*)&Ah[wr*64 + i*16 + lm][lg*8];
      bh[i] = *(const s16x8*)&Bh[wc*64 + i*16 + lm][lg*8];
    }
#pragma unroll
    for (int i = 0; i < 4; ++i)
#pragma unroll
      for (int j = 0; j < 4; ++j)
        acc[i][j] = __builtin_amdgcn_mfma_f32_16x16x32_bf16(ah[i], bh[j], acc[i][j], 0, 0, 0);
    __syncthreads();
  }
#pragma unroll
  for (int i = 0; i < 4; ++i)
#pragma unroll
    for (int j = 0; j < 4; ++j) {
      const int colg = n0 + wc*64 + j*16 + lm;
      const int rowb = m0 + wr*64 + i*16 + lg*4;
      const float bcol = bias[colg];
      if constexpr (OUT_MODE == 2) {
        float* O = (float*)Out;
#pragma unroll
        for (int r = 0; r < 4; ++r)
          O[(size_t)(rowb + r) * DM + colg] = acc[i][j][r] + bcol;
      } else if constexpr (OUT_MODE == 0) {
        u16* O = (u16*)Out;
#pragma unroll
        for (int r = 0; r < 4; ++r)
          O[(size_t)(rowb + r) * DM + colg] = f2bf(acc[i][j][r] + bcol);
      } else {  // vT transposed bf16
        u16* OT = (u16*)Out;
        const int bb = rowb >> 11, key = rowb & 2047;
        const int hh = colg >> 6, dv = colg & 63;
        s16x4 pk;
#pragma unroll
        for (int r = 0; r < 4; ++r) pk[r] = (short)f2bf(acc[i][j][r] + bcol);
        *(s16x4*)(OT + (((size_t)bb*NH + hh)*HD + dv)*SLK + key) = pk;
      }
    }
}

// ---------------------------------------------------------------------------
// Flash attention, MFMA, plain bf16. Block = (qt64, h, b), 4 waves.
// QK^T 2 MFMAs/frag, PV 2 MFMAs/frag. Writes wv bf16 + (m,l).
// ---------------------------------------------------------------------------
__global__ __launch_bounds__(256) void attn_mfma_k(
    const u16* __restrict__ qb, const u16* __restrict__ kb,
    const u16* __restrict__ vT, const u32* __restrict__ mbits,
    u16* __restrict__ wv, float* __restrict__ ml) {
  __shared__ u16 ks[64][72];
  __shared__ u16 vs[64][72];
  __shared__ u16 ps[4][16][72];
  const int qt = blockIdx.x, h = blockIdx.y, b = blockIdx.z;
  const int t = threadIdx.x, wid = t >> 6, lane = t & 63, lg = lane >> 4, lm = lane & 15;
  const int q0 = qt * 64, qw = q0 + wid * 16;
  s16x8 qh[2];
#pragma unroll
  for (int s = 0; s < 2; ++s) {
    size_t off = ((size_t)(b*SLQ + qw + lm)) * DM + h*HD + s*32 + lg*8;
    qh[s] = *(const s16x8*)(qb + off);
  }
  f32x4 O[4];
#pragma unroll
  for (int j = 0; j < 4; ++j) O[j] = (f32x4)(0.0f);
  float m_r[4] = {-INFINITY, -INFINITY, -INFINITY, -INFINITY};
  float l_r[4] = {0.f, 0.f, 0.f, 0.f};
  const int srow = t >> 2, sch = t & 3;
  for (int j0 = 0; j0 < SLK; j0 += 64) {
    {
      size_t koff = ((size_t)(b*SLK + j0 + srow)) * DM + h*HD + sch*16;
      *(s16x8*)&ks[srow][sch*16]     = *(const s16x8*)(kb + koff);
      *(s16x8*)&ks[srow][sch*16 + 8] = *(const s16x8*)(kb + koff + 8);
      size_t voff = (((size_t)b*NH + h)*HD + srow)*SLK + j0 + sch*16;
      *(s16x8*)&vs[srow][sch*16]     = *(const s16x8*)(vT + voff);
      *(s16x8*)&vs[srow][sch*16 + 8] = *(const s16x8*)(vT + voff + 8);
    }
    __syncthreads();
    // QK^T
    f32x4 sc[4];
#pragma unroll
    for (int j = 0; j < 4; ++j) {
      s16x8 kh0 = *(const s16x8*)&ks[j*16 + lm][lg*8];
      s16x8 kh1 = *(const s16x8*)&ks[j*16 + lm][32 + lg*8];
      f32x4 c = (f32x4)(0.0f);
      c = __builtin_amdgcn_mfma_f32_16x16x32_bf16(qh[0], kh0, c, 0, 0, 0);
      c = __builtin_amdgcn_mfma_f32_16x16x32_bf16(qh[1], kh1, c, 0, 0, 0);
      sc[j] = c;
    }
    // mask + online softmax per q-row (reg r)
#pragma unroll
    for (int r = 0; r < 4; ++r) {
      size_t mrow = ((size_t)(b*SLQ + qw + lg*4 + r)) * (SLK/32) + (j0 >> 5);
      u32 w0 = mbits[mrow], w1 = mbits[mrow + 1];
      float sv[4];
#pragma unroll
      for (int j = 0; j < 4; ++j) {
        u32 w = (j < 2) ? w0 : w1;
        int bit = (w >> ((j*16 + lm) & 31)) & 1;
        sv[j] = bit ? sc[j][r] * 0.125f : -1e9f;
      }
      float mx = fmaxf(fmaxf(sv[0], sv[1]), fmaxf(sv[2], sv[3]));
#pragma unroll
      for (int off = 1; off < 16; off <<= 1) mx = fmaxf(mx, __shfl_xor(mx, off, 64));
      float mnew  = fmaxf(m_r[r], mx);
      float alpha = __expf(m_r[r] - mnew);
      m_r[r] = mnew;
      float rs = 0.f;
      float p[4];
#pragma unroll
      for (int j = 0; j < 4; ++j) { p[j] = __expf(sv[j] - mnew); rs += p[j]; }
#pragma unroll
      for (int off = 1; off < 16; off <<= 1) rs += __shfl_xor(rs, off, 64);
      l_r[r] = l_r[r] * alpha + rs;
#pragma unroll
      for (int j = 0; j < 4; ++j) O[j][r] *= alpha;
#pragma unroll
      for (int j = 0; j < 4; ++j) ps[wid][lg*4 + r][j*16 + lm] = f2bf(p[j]);
    }
    // PV
    {
      s16x8 pa0 = *(const s16x8*)&ps[wid][lm][lg*8];
      s16x8 pa1 = *(const s16x8*)&ps[wid][lm][32 + lg*8];
#pragma unroll
      for (int j = 0; j < 4; ++j) {
        s16x8 vb0 = *(const s16x8*)&vs[j*16 + lm][lg*8];
        s16x8 vb1 = *(const s16x8*)&vs[j*16 + lm][32 + lg*8];
        O[j] = __builtin_amdgcn_mfma_f32_16x16x32_bf16(pa0, vb0, O[j], 0, 0, 0);
        O[j] = __builtin_amdgcn_mfma_f32_16x16x32_bf16(pa1, vb1, O[j], 0, 0, 0);
      }
    }
    __syncthreads();
  }
#pragma unroll
  for (int j = 0; j < 4; ++j)
#pragma unroll
    for (int r = 0; r < 4; ++r) {
      float v = O[j][r] / l_r[r];
      size_t row = (size_t)(b*SLQ + qw + lg*4 + r);
      wv[row*DM + h*HD + j*16 + lm] = f2bf(v);
    }
  if (lm == 0) {
#pragma unroll
    for (int r = 0; r < 4; ++r) {
      float* mp = ml + ((size_t)(b*NH + h)*SLQ + qw + lg*4 + r) * 2;
      mp[0] = m_r[r]; mp[1] = l_r[r];
    }
  }
}

// ---------------------------------------------------------------------------
// weight_mean: block = (jt-group of 4 x 64 keys, qt64, b); loop h in-block.
// Scores bitwise-match attn (same bf16 inputs, same MFMA chain order).
// ---------------------------------------------------------------------------
__global__ __launch_bounds__(256) void wmean_mfma_k(
    const u16* __restrict__ qb, const u16* __restrict__ kb,
    const u32* __restrict__ mbits, const float* __restrict__ ml,
    float* __restrict__ out1) {
  __shared__ u16 ks[64][72];
  const int t = threadIdx.x, wid = t >> 6, lane = t & 63, lg = lane >> 4, lm = lane & 15;
  const int q0 = blockIdx.y * 64, b = blockIdx.z, qw = q0 + wid * 16;
  const int srow = t >> 2, sch = t & 3;
  for (int jt = 0; jt < 4; ++jt) {
    const int j0 = blockIdx.x * 256 + jt * 64;
    f32x4 wm[4];
#pragma unroll
    for (int j = 0; j < 4; ++j) wm[j] = (f32x4)(0.0f);
    u32 w0[4], w1[4];
#pragma unroll
    for (int r = 0; r < 4; ++r) {
      size_t mrow = ((size_t)(b*SLQ + qw + lg*4 + r)) * (SLK/32) + (j0 >> 5);
      w0[r] = mbits[mrow]; w1[r] = mbits[mrow + 1];
    }
    for (int h = 0; h < NH; ++h) {
      __syncthreads();
      {
        size_t koff = ((size_t)(b*SLK + j0 + srow)) * DM + h*HD + sch*16;
        *(s16x8*)&ks[srow][sch*16]     = *(const s16x8*)(kb + koff);
        *(s16x8*)&ks[srow][sch*16 + 8] = *(const s16x8*)(kb + koff + 8);
      }
      __syncthreads();
      s16x8 qh0, qh1;
      {
        size_t off = ((size_t)(b*SLQ + qw + lm)) * DM + h*HD + lg*8;
        qh0 = *(const s16x8*)(qb + off);
        qh1 = *(const s16x8*)(qb + off + 32);
      }
      float mr[4], li[4];
#pragma unroll
      for (int r = 0; r < 4; ++r) {
        const float* mp = ml + ((size_t)(b*NH + h)*SLQ + qw + lg*4 + r) * 2;
        mr[r] = mp[0]; li[r] = 1.0f / mp[1];
      }
#pragma unroll
      for (int j = 0; j < 4; ++j) {
        s16x8 kh0 = *(const s16x8*)&ks[j*16 + lm][lg*8];
        s16x8 kh1 = *(const s16x8*)&ks[j*16 + lm][32 + lg*8];
        f32x4 c = (f32x4)(0.0f);
        c = __builtin_amdgcn_mfma_f32_16x16x32_bf16(qh0, kh0, c, 0, 0, 0);
        c = __builtin_amdgcn_mfma_f32_16x16x32_bf16(qh1, kh1, c, 0, 0, 0);
#pragma unroll
        for (int r = 0; r < 4; ++r) {
          u32 w = (j < 2) ? w0[r] : w1[r];
          int bit = (w >> ((j*16 + lm) & 31)) & 1;
          float wvv = bit ? __expf(c[r] * 0.125f - mr[r]) * li[r] : 0.f;
          wm[j][r] += wvv;
        }
      }
    }
#pragma unroll
    for (int j = 0; j < 4; ++j)
#pragma unroll
      for (int r = 0; r < 4; ++r)
        out1[((size_t)b*SLQ + q0 + wid*16 + lg*4 + r) * SLK + j0 + j*16 + lm]
            = wm[j][r] * (1.0f / NH);
  }
}

// ---------------------------------------------------------------------------
extern "C" void kernel_launch(void* const* d_in, const int* in_sizes, int n_in,
                              void* d_out, int out_size, void* d_ws, size_t ws_size,
                              hipStream_t stream) {
  const float* mq    = (const float*)d_in[0];
  const float* reply = (const float*)d_in[1];
  const int*   maskp = (const int*)  d_in[2];
  const float* Wq = (const float*)d_in[3];
  const float* bq = (const float*)d_in[4];
  const float* Wk = (const float*)d_in[5];
  const float* bk = (const float*)d_in[6];
  const float* Wv = (const float*)d_in[7];
  const float* bv = (const float*)d_in[8];
  const float* Wo = (const float*)d_in[9];
  const float* bo = (const float*)d_in[10];

  float* out0 = (float*)d_out;
  float* out1 = out0 + (size_t)NB*SLQ*DM;

  // workspace carve -- total ~82 MB
  char* w = (char*)d_ws;
  auto carve = [&](size_t bytes) { char* p = w; w += bytes; return p; };
  u16* WqT = (u16*)carve((size_t)DM*DM*2);
  u16* WkT = (u16*)carve((size_t)DM*DM*2);
  u16* WvT = (u16*)carve((size_t)DM*DM*2);
  u16* WoT = (u16*)carve((size_t)DM*DM*2);
  u16* mqb = (u16*)carve((size_t)NB*SLQ*DM*2);
  u16* rpb = (u16*)carve((size_t)NB*SLK*DM*2);
  u16* qbf = (u16*)carve((size_t)NB*SLQ*DM*2);
  u16* kbf = (u16*)carve((size_t)NB*SLK*DM*2);
  u16* vT  = (u16*)carve((size_t)NB*SLK*DM*2);
  u16* wvb = (u16*)carve((size_t)NB*SLQ*DM*2);
  float* mlb = (float*)carve((size_t)NB*NH*SLQ*2*4);
  unsigned long long* mbits = (unsigned long long*)carve((size_t)NB*SLQ*SLK/8);

  cvt_bf16_k<<<512, 256, 0, stream>>>(mq,    mqb, NB*SLQ*DM);
  cvt_bf16_k<<<512, 256, 0, stream>>>(reply, rpb, NB*SLK*DM);
  maskbits_k<<<256, 256, 0, stream>>>(maskp, mbits, NB*SLQ*SLK/64);
  dim3 tg(16, 16);
  convT_k<<<tg, 256, 0, stream>>>(Wq, WqT);
  convT_k<<<tg, 256, 0, stream>>>(Wk, WkT);
  convT_k<<<tg, 256, 0, stream>>>(Wv, WvT);
  convT_k<<<tg, 256, 0, stream>>>(Wo, WoT);

  gemm_bf16_k<0><<<dim3(DM/128, (NB*SLQ)/128), 256, 0, stream>>>(mqb, WqT, bq, qbf);
  gemm_bf16_k<0><<<dim3(DM/128, (NB*SLK)/128), 256, 0, stream>>>(rpb, WkT, bk, kbf);
  gemm_bf16_k<1><<<dim3(DM/128, (NB*SLK)/128), 256, 0, stream>>>(rpb, WvT, bv, vT);

  attn_mfma_k<<<dim3(SLQ/64, NH, NB), 256, 0, stream>>>(
      qbf, kbf, vT, (const u32*)mbits, wvb, mlb);

  wmean_mfma_k<<<dim3(SLK/256, SLQ/64, NB), 256, 0, stream>>>(
      qbf, kbf, (const u32*)mbits, mlb, out1);

  gemm_bf16_k<2><<<dim3(DM/128, (NB*SLQ)/128), 256, 0, stream>>>(wvb, WoT, bo, out0);
}

// Round 6
// 369.608 us; speedup vs baseline: 4.2023x; 1.1284x over previous
//
#include <hip/hip_runtime.h>
#include <math.h>

#define NB   4
#define NH   16
#define SLQ  1024
#define SLK  2048
#define DM   1024
#define HD   64

typedef __attribute__((ext_vector_type(8))) short s16x8;
typedef __attribute__((ext_vector_type(4))) short s16x4;
typedef __attribute__((ext_vector_type(4))) float f32x4;
typedef unsigned short u16;
typedef unsigned int   u32;

__device__ inline u16 f2bf(float f) {
  u32 u = __float_as_uint(f);
  u32 r = u + 0x7fffu + ((u >> 16) & 1u);
  return (u16)(r >> 16);
}
__device__ inline float bf2f(u16 h) { return __uint_as_float(((u32)h) << 16); }

// async global->LDS, 16B per lane; LDS dest must be wave-uniform base.
__device__ __forceinline__ void gl16(const void* g, void* l) {
  __builtin_amdgcn_global_load_lds(
      (const __attribute__((address_space(1))) unsigned int*)g,
      (__attribute__((address_space(3))) unsigned int*)l, 16, 0, 0);
}

// ---------------------------------------------------------------------------
// f32 -> bf16 (plain), vectorized 8/thread, grid-stride.
// ---------------------------------------------------------------------------
__global__ __launch_bounds__(256) void cvt_bf16_k(
    const float* __restrict__ src, u16* __restrict__ dst, int n) {
  int stride = gridDim.x * blockDim.x * 8;
  for (int i = (blockIdx.x * blockDim.x + threadIdx.x) * 8; i < n; i += stride) {
    float4 a = *(const float4*)(src + i);
    float4 b = *(const float4*)(src + i + 4);
    s16x8 o;
    o[0] = (short)f2bf(a.x); o[1] = (short)f2bf(a.y);
    o[2] = (short)f2bf(a.z); o[3] = (short)f2bf(a.w);
    o[4] = (short)f2bf(b.x); o[5] = (short)f2bf(b.y);
    o[6] = (short)f2bf(b.z); o[7] = (short)f2bf(b.w);
    *(s16x8*)(dst + i) = o;
  }
}

// ---------------------------------------------------------------------------
// mask -> bitmask (1 bit per (q,key)); wave ballot, 64 keys per wave-iter.
// ---------------------------------------------------------------------------
__global__ __launch_bounds__(256) void maskbits_k(
    const int* __restrict__ mask, unsigned long long* __restrict__ bits, int nwords) {
  int gw   = (blockIdx.x * blockDim.x + threadIdx.x) >> 6;
  int lane = threadIdx.x & 63;
  int nw   = (gridDim.x * blockDim.x) >> 6;
  for (int w = gw; w < nwords; w += nw) {
    int m = mask[(size_t)w * 64 + lane];
    unsigned long long b = __ballot(m != 0);
    if (lane == 0) bits[w] = b;
  }
}

// ---------------------------------------------------------------------------
// W[1024][1024] f32 -> WT [n][k] bf16 (transposed, plain).
// ---------------------------------------------------------------------------
__global__ __launch_bounds__(256) void convT_k(
    const float* __restrict__ W, u16* __restrict__ T) {
  __shared__ float ts[64][68];
  const int t = threadIdx.x;
  const int r0 = blockIdx.y * 64, c0 = blockIdx.x * 64;
  const int rr = t >> 4, cc = t & 15;
#pragma unroll
  for (int p = 0; p < 4; ++p) {
    float4 v = *(const float4*)(W + (size_t)(r0 + rr + p*16) * DM + c0 + cc*4);
    *(float4*)&ts[rr + p*16][cc*4] = v;
  }
  __syncthreads();
  const int c = t >> 2, ch = t & 3;
  s16x8 h0, h1;
#pragma unroll
  for (int i = 0; i < 8; ++i) {
    h0[i] = (short)f2bf(ts[ch*16 + i][c]);
    h1[i] = (short)f2bf(ts[ch*16 + 8 + i][c]);
  }
  size_t base = (size_t)(c0 + c) * DM + r0 + ch*16;
  *(s16x8*)(T + base) = h0; *(s16x8*)(T + base + 8) = h1;
}

// ---------------------------------------------------------------------------
// bf16 MFMA GEMM: C[M,1024] = A[M,1024] @ W + bias.  A bf16 [M][1024],
// BT bf16 [n][k].  128x128 tile, BK=32, 4 waves (2x2), 4x4 frags/wave.
// Staging: global_load_lds dwordx4 (1KB/wave-op), LINEAR LDS [128][32]
// (gload_lds requires contiguous dest, no pad).
// OUT_MODE: 0 = bf16 natural; 1 = bf16 transposed vT [b][h][dv][SLK];
//           2 = f32 natural.
// ---------------------------------------------------------------------------
template<int OUT_MODE>
__global__ __launch_bounds__(256) void gemm_bf16_k(
    const u16* __restrict__ Ab, const u16* __restrict__ BT,
    const float* __restrict__ bias, void* __restrict__ Out) {
  __shared__ u16 Ah[128 * 32];
  __shared__ u16 Bh[128 * 32];
  const int t = threadIdx.x;
  const int m0 = blockIdx.y * 128, n0 = blockIdx.x * 128;
  const int wid = t >> 6, lane = t & 63, lg = lane >> 4, lm = lane & 15;
  const int wr = wid >> 1, wc = wid & 1;
  f32x4 acc[4][4];
#pragma unroll
  for (int i = 0; i < 4; ++i)
#pragma unroll
    for (int j = 0; j < 4; ++j) acc[i][j] = (f32x4)(0.0f);

  // staging geometry: chunk c = 16 rows x 32 u16 = 1KB; wave stages chunks
  // {wid*2, wid*2+1} of A and B. lane covers row c*16+(lane>>2), u16 piece
  // (lane&3)*8; LDS linear so dest = base + lane*16B matches row-major.
  const int c0 = wid * 2, c1 = wid * 2 + 1;
  const int sr0 = c0 * 16 + (lane >> 2), sr1 = c1 * 16 + (lane >> 2);
  const int spc = (lane & 3) * 8;
  for (int k0 = 0; k0 < DM; k0 += 32) {
    gl16(Ab + (size_t)(m0 + sr0) * DM + k0 + spc, &Ah[c0 * 512]);
    gl16(Ab + (size_t)(m0 + sr1) * DM + k0 + spc, &Ah[c1 * 512]);
    gl16(BT + (size_t)(n0 + sr0) * DM + k0 + spc, &Bh[c0 * 512]);
    gl16(BT + (size_t)(n0 + sr1) * DM + k0 + spc, &Bh[c1 * 512]);
    __syncthreads();
    s16x8 ah[4], bh[4];
#pragma unroll
    for (int i = 0; i < 4; ++i) {
      ah[i] = *(const s16x8*)&Ah[(wr*64 + i*16 + lm) * 32 + lg*8];
      bh[i] = *(const s16x8*)&Bh[(wc*64 + i*16 + lm) * 32 + lg*8];
    }
#pragma unroll
    for (int i = 0; i < 4; ++i)
#pragma unroll
      for (int j = 0; j < 4; ++j)
        acc[i][j] = __builtin_amdgcn_mfma_f32_16x16x32_bf16(ah[i], bh[j], acc[i][j], 0, 0, 0);
    __syncthreads();
  }
#pragma unroll
  for (int i = 0; i < 4; ++i)
#pragma unroll
    for (int j = 0; j < 4; ++j) {
      const int colg = n0 + wc*64 + j*16 + lm;
      const int rowb = m0 + wr*64 + i*16 + lg*4;
      const float bcol = bias[colg];
      if constexpr (OUT_MODE == 2) {
        float* O = (float*)Out;
#pragma unroll
        for (int r = 0; r < 4; ++r)
          O[(size_t)(rowb + r) * DM + colg] = acc[i][j][r] + bcol;
      } else if constexpr (OUT_MODE == 0) {
        u16* O = (u16*)Out;
#pragma unroll
        for (int r = 0; r < 4; ++r)
          O[(size_t)(rowb + r) * DM + colg] = f2bf(acc[i][j][r] + bcol);
      } else {  // vT transposed bf16
        u16* OT = (u16*)Out;
        const int bb = rowb >> 11, key = rowb & 2047;
        const int hh = colg >> 6, dv = colg & 63;
        s16x4 pk;
#pragma unroll
        for (int r = 0; r < 4; ++r) pk[r] = (short)f2bf(acc[i][j][r] + bcol);
        *(s16x4*)(OT + (((size_t)bb*NH + hh)*HD + dv)*SLK + key) = pk;
      }
    }
}

// ---------------------------------------------------------------------------
// Flash attention, MFMA, plain bf16. Block = (qt64, h, b), 4 waves.
// Deferred-max softmax: stale running max m (update only when a tile's
// local max exceeds m+8, tested with one __all); l kept as per-lane
// partials, reduced once at the end. Steady state: ZERO cross-lane shuffles
// per tile. w = exp(s-m)/l is exact for any consistent m (wmean uses the
// same stored m,l).
// ---------------------------------------------------------------------------
__global__ __launch_bounds__(256) void attn_mfma_k(
    const u16* __restrict__ qb, const u16* __restrict__ kb,
    const u16* __restrict__ vT, const u32* __restrict__ mbits,
    u16* __restrict__ wv, float* __restrict__ ml) {
  __shared__ u16 ks[64][72];
  __shared__ u16 vs[64][72];
  __shared__ u16 ps[4][16][72];
  const int qt = blockIdx.x, h = blockIdx.y, b = blockIdx.z;
  const int t = threadIdx.x, wid = t >> 6, lane = t & 63, lg = lane >> 4, lm = lane & 15;
  const int q0 = qt * 64, qw = q0 + wid * 16;
  s16x8 qh[2];
#pragma unroll
  for (int s = 0; s < 2; ++s) {
    size_t off = ((size_t)(b*SLQ + qw + lm)) * DM + h*HD + s*32 + lg*8;
    qh[s] = *(const s16x8*)(qb + off);
  }
  f32x4 O[4];
#pragma unroll
  for (int j = 0; j < 4; ++j) O[j] = (f32x4)(0.0f);
  float m_r[4] = {-INFINITY, -INFINITY, -INFINITY, -INFINITY};
  float l_r[4] = {0.f, 0.f, 0.f, 0.f};   // per-lane partials (16 lanes/row)
  const int srow = t >> 2, sch = t & 3;
  for (int j0 = 0; j0 < SLK; j0 += 64) {
    {
      size_t koff = ((size_t)(b*SLK + j0 + srow)) * DM + h*HD + sch*16;
      *(s16x8*)&ks[srow][sch*16]     = *(const s16x8*)(kb + koff);
      *(s16x8*)&ks[srow][sch*16 + 8] = *(const s16x8*)(kb + koff + 8);
      size_t voff = (((size_t)b*NH + h)*HD + srow)*SLK + j0 + sch*16;
      *(s16x8*)&vs[srow][sch*16]     = *(const s16x8*)(vT + voff);
      *(s16x8*)&vs[srow][sch*16 + 8] = *(const s16x8*)(vT + voff + 8);
    }
    __syncthreads();
    // QK^T
    f32x4 sc[4];
#pragma unroll
    for (int j = 0; j < 4; ++j) {
      s16x8 kh0 = *(const s16x8*)&ks[j*16 + lm][lg*8];
      s16x8 kh1 = *(const s16x8*)&ks[j*16 + lm][32 + lg*8];
      f32x4 c = (f32x4)(0.0f);
      c = __builtin_amdgcn_mfma_f32_16x16x32_bf16(qh[0], kh0, c, 0, 0, 0);
      c = __builtin_amdgcn_mfma_f32_16x16x32_bf16(qh[1], kh1, c, 0, 0, 0);
      sc[j] = c;
    }
    // mask + deferred-max online softmax per q-row (reg r)
#pragma unroll
    for (int r = 0; r < 4; ++r) {
      size_t mrow = ((size_t)(b*SLQ + qw + lg*4 + r)) * (SLK/32) + (j0 >> 5);
      u32 w0 = mbits[mrow], w1 = mbits[mrow + 1];
      float sv[4];
#pragma unroll
      for (int j = 0; j < 4; ++j) {
        u32 w = (j < 2) ? w0 : w1;
        int bit = (w >> ((j*16 + lm) & 31)) & 1;
        sv[j] = bit ? sc[j][r] * 0.125f : -1e9f;
      }
      float pmax = fmaxf(fmaxf(sv[0], sv[1]), fmaxf(sv[2], sv[3]));
      if (!__all(pmax <= m_r[r] + 8.0f)) {       // slow path: ~tile 0 only
        float mx = pmax;
#pragma unroll
        for (int off = 1; off < 16; off <<= 1) mx = fmaxf(mx, __shfl_xor(mx, off, 64));
        float mnew  = fmaxf(m_r[r], mx);
        float alpha = __expf(m_r[r] - mnew);     // m=-inf -> alpha=0
        m_r[r] = mnew;
        l_r[r] *= alpha;
#pragma unroll
        for (int j = 0; j < 4; ++j) O[j][r] *= alpha;
      }
      float p0 = __expf(sv[0] - m_r[r]);
      float p1 = __expf(sv[1] - m_r[r]);
      float p2 = __expf(sv[2] - m_r[r]);
      float p3 = __expf(sv[3] - m_r[r]);
      l_r[r] += (p0 + p1) + (p2 + p3);
      ps[wid][lg*4 + r][0*16 + lm] = f2bf(p0);
      ps[wid][lg*4 + r][1*16 + lm] = f2bf(p1);
      ps[wid][lg*4 + r][2*16 + lm] = f2bf(p2);
      ps[wid][lg*4 + r][3*16 + lm] = f2bf(p3);
    }
    // PV
    {
      s16x8 pa0 = *(const s16x8*)&ps[wid][lm][lg*8];
      s16x8 pa1 = *(const s16x8*)&ps[wid][lm][32 + lg*8];
#pragma unroll
      for (int j = 0; j < 4; ++j) {
        s16x8 vb0 = *(const s16x8*)&vs[j*16 + lm][lg*8];
        s16x8 vb1 = *(const s16x8*)&vs[j*16 + lm][32 + lg*8];
        O[j] = __builtin_amdgcn_mfma_f32_16x16x32_bf16(pa0, vb0, O[j], 0, 0, 0);
        O[j] = __builtin_amdgcn_mfma_f32_16x16x32_bf16(pa1, vb1, O[j], 0, 0, 0);
      }
    }
    __syncthreads();
  }
  // final l reduction across the 16 lanes of each row (once)
#pragma unroll
  for (int r = 0; r < 4; ++r) {
#pragma unroll
    for (int off = 1; off < 16; off <<= 1) l_r[r] += __shfl_xor(l_r[r], off, 64);
  }
#pragma unroll
  for (int j = 0; j < 4; ++j)
#pragma unroll
    for (int r = 0; r < 4; ++r) {
      float v = O[j][r] / l_r[r];
      size_t row = (size_t)(b*SLQ + qw + lg*4 + r);
      wv[row*DM + h*HD + j*16 + lm] = f2bf(v);
    }
  if (lm == 0) {
#pragma unroll
    for (int r = 0; r < 4; ++r) {
      float* mp = ml + ((size_t)(b*NH + h)*SLQ + qw + lg*4 + r) * 2;
      mp[0] = m_r[r]; mp[1] = l_r[r];
    }
  }
}

// ---------------------------------------------------------------------------
// weight_mean: block = (jt-group of 4 x 64 keys, qt64, b); loop h in-block.
// w = exp(s/8 - m)/l with attn's stored (m,l); masked -> 0; mean over h.
// ---------------------------------------------------------------------------
__global__ __launch_bounds__(256) void wmean_mfma_k(
    const u16* __restrict__ qb, const u16* __restrict__ kb,
    const u32* __restrict__ mbits, const float* __restrict__ ml,
    float* __restrict__ out1) {
  __shared__ u16 ks[64][72];
  const int t = threadIdx.x, wid = t >> 6, lane = t & 63, lg = lane >> 4, lm = lane & 15;
  const int q0 = blockIdx.y * 64, b = blockIdx.z, qw = q0 + wid * 16;
  const int srow = t >> 2, sch = t & 3;
  for (int jt = 0; jt < 4; ++jt) {
    const int j0 = blockIdx.x * 256 + jt * 64;
    f32x4 wm[4];
#pragma unroll
    for (int j = 0; j < 4; ++j) wm[j] = (f32x4)(0.0f);
    u32 w0[4], w1[4];
#pragma unroll
    for (int r = 0; r < 4; ++r) {
      size_t mrow = ((size_t)(b*SLQ + qw + lg*4 + r)) * (SLK/32) + (j0 >> 5);
      w0[r] = mbits[mrow]; w1[r] = mbits[mrow + 1];
    }
    for (int h = 0; h < NH; ++h) {
      __syncthreads();
      {
        size_t koff = ((size_t)(b*SLK + j0 + srow)) * DM + h*HD + sch*16;
        *(s16x8*)&ks[srow][sch*16]     = *(const s16x8*)(kb + koff);
        *(s16x8*)&ks[srow][sch*16 + 8] = *(const s16x8*)(kb + koff + 8);
      }
      __syncthreads();
      s16x8 qh0, qh1;
      {
        size_t off = ((size_t)(b*SLQ + qw + lm)) * DM + h*HD + lg*8;
        qh0 = *(const s16x8*)(qb + off);
        qh1 = *(const s16x8*)(qb + off + 32);
      }
      float mr[4], li[4];
#pragma unroll
      for (int r = 0; r < 4; ++r) {
        const float* mp = ml + ((size_t)(b*NH + h)*SLQ + qw + lg*4 + r) * 2;
        mr[r] = mp[0]; li[r] = 1.0f / mp[1];
      }
#pragma unroll
      for (int j = 0; j < 4; ++j) {
        s16x8 kh0 = *(const s16x8*)&ks[j*16 + lm][lg*8];
        s16x8 kh1 = *(const s16x8*)&ks[j*16 + lm][32 + lg*8];
        f32x4 c = (f32x4)(0.0f);
        c = __builtin_amdgcn_mfma_f32_16x16x32_bf16(qh0, kh0, c, 0, 0, 0);
        c = __builtin_amdgcn_mfma_f32_16x16x32_bf16(qh1, kh1, c, 0, 0, 0);
#pragma unroll
        for (int r = 0; r < 4; ++r) {
          u32 w = (j < 2) ? w0[r] : w1[r];
          int bit = (w >> ((j*16 + lm) & 31)) & 1;
          float wvv = bit ? __expf(c[r] * 0.125f - mr[r]) * li[r] : 0.f;
          wm[j][r] += wvv;
        }
      }
    }
#pragma unroll
    for (int j = 0; j < 4; ++j)
#pragma unroll
      for (int r = 0; r < 4; ++r)
        out1[((size_t)b*SLQ + q0 + wid*16 + lg*4 + r) * SLK + j0 + j*16 + lm]
            = wm[j][r] * (1.0f / NH);
  }
}

// ---------------------------------------------------------------------------
extern "C" void kernel_launch(void* const* d_in, const int* in_sizes, int n_in,
                              void* d_out, int out_size, void* d_ws, size_t ws_size,
                              hipStream_t stream) {
  const float* mq    = (const float*)d_in[0];
  const float* reply = (const float*)d_in[1];
  const int*   maskp = (const int*)  d_in[2];
  const float* Wq = (const float*)d_in[3];
  const float* bq = (const float*)d_in[4];
  const float* Wk = (const float*)d_in[5];
  const float* bk = (const float*)d_in[6];
  const float* Wv = (const float*)d_in[7];
  const float* bv = (const float*)d_in[8];
  const float* Wo = (const float*)d_in[9];
  const float* bo = (const float*)d_in[10];

  float* out0 = (float*)d_out;
  float* out1 = out0 + (size_t)NB*SLQ*DM;

  // workspace carve -- total ~82 MB
  char* w = (char*)d_ws;
  auto carve = [&](size_t bytes) { char* p = w; w += bytes; return p; };
  u16* WqT = (u16*)carve((size_t)DM*DM*2);
  u16* WkT = (u16*)carve((size_t)DM*DM*2);
  u16* WvT = (u16*)carve((size_t)DM*DM*2);
  u16* WoT = (u16*)carve((size_t)DM*DM*2);
  u16* mqb = (u16*)carve((size_t)NB*SLQ*DM*2);
  u16* rpb = (u16*)carve((size_t)NB*SLK*DM*2);
  u16* qbf = (u16*)carve((size_t)NB*SLQ*DM*2);
  u16* kbf = (u16*)carve((size_t)NB*SLK*DM*2);
  u16* vT  = (u16*)carve((size_t)NB*SLK*DM*2);
  u16* wvb = (u16*)carve((size_t)NB*SLQ*DM*2);
  float* mlb = (float*)carve((size_t)NB*NH*SLQ*2*4);
  unsigned long long* mbits = (unsigned long long*)carve((size_t)NB*SLQ*SLK/8);

  cvt_bf16_k<<<512, 256, 0, stream>>>(mq,    mqb, NB*SLQ*DM);
  cvt_bf16_k<<<512, 256, 0, stream>>>(reply, rpb, NB*SLK*DM);
  maskbits_k<<<256, 256, 0, stream>>>(maskp, mbits, NB*SLQ*SLK/64);
  dim3 tg(16, 16);
  convT_k<<<tg, 256, 0, stream>>>(Wq, WqT);
  convT_k<<<tg, 256, 0, stream>>>(Wk, WkT);
  convT_k<<<tg, 256, 0, stream>>>(Wv, WvT);
  convT_k<<<tg, 256, 0, stream>>>(Wo, WoT);

  gemm_bf16_k<0><<<dim3(DM/128, (NB*SLQ)/128), 256, 0, stream>>>(mqb, WqT, bq, qbf);
  gemm_bf16_k<0><<<dim3(DM/128, (NB*SLK)/128), 256, 0, stream>>>(rpb, WkT, bk, kbf);
  gemm_bf16_k<1><<<dim3(DM/128, (NB*SLK)/128), 256, 0, stream>>>(rpb, WvT, bv, vT);

  attn_mfma_k<<<dim3(SLQ/64, NH, NB), 256, 0, stream>>>(
      qbf, kbf, vT, (const u32*)mbits, wvb, mlb);

  wmean_mfma_k<<<dim3(SLK/256, SLQ/64, NB), 256, 0, stream>>>(
      qbf, kbf, (const u32*)mbits, mlb, out1);

  gemm_bf16_k<2><<<dim3(DM/128, (NB*SLQ)/128), 256, 0, stream>>>(wvb, WoT, bo, out0);
}

// Round 7
// 327.044 us; speedup vs baseline: 4.7492x; 1.1301x over previous
//
#include <hip/hip_runtime.h>
#include <math.h>

#define NB   4
#define NH   16
#define SLQ  1024
#define SLK  2048
#define DM   1024
#define HD   64

typedef __attribute__((ext_vector_type(8))) short s16x8;
typedef __attribute__((ext_vector_type(4))) short s16x4;
typedef __attribute__((ext_vector_type(4))) float f32x4;
typedef unsigned short u16;
typedef unsigned int   u32;

__device__ inline u16 f2bf(float f) {
  u32 u = __float_as_uint(f);
  u32 r = u + 0x7fffu + ((u >> 16) & 1u);
  return (u16)(r >> 16);
}
__device__ inline float bf2f(u16 h) { return __uint_as_float(((u32)h) << 16); }

// async global->LDS, 16B per lane; LDS dest must be wave-uniform base.
__device__ __forceinline__ void gl16(const void* g, void* l) {
  __builtin_amdgcn_global_load_lds(
      (const __attribute__((address_space(1))) unsigned int*)g,
      (__attribute__((address_space(3))) unsigned int*)l, 16, 0, 0);
}

// ---------------------------------------------------------------------------
// f32 -> bf16 (plain), vectorized 8/thread, grid-stride.
// ---------------------------------------------------------------------------
__global__ __launch_bounds__(256) void cvt_bf16_k(
    const float* __restrict__ src, u16* __restrict__ dst, int n) {
  int stride = gridDim.x * blockDim.x * 8;
  for (int i = (blockIdx.x * blockDim.x + threadIdx.x) * 8; i < n; i += stride) {
    float4 a = *(const float4*)(src + i);
    float4 b = *(const float4*)(src + i + 4);
    s16x8 o;
    o[0] = (short)f2bf(a.x); o[1] = (short)f2bf(a.y);
    o[2] = (short)f2bf(a.z); o[3] = (short)f2bf(a.w);
    o[4] = (short)f2bf(b.x); o[5] = (short)f2bf(b.y);
    o[6] = (short)f2bf(b.z); o[7] = (short)f2bf(b.w);
    *(s16x8*)(dst + i) = o;
  }
}

// ---------------------------------------------------------------------------
// mask -> bitmask (1 bit per (q,key)); wave ballot, 64 keys per wave-iter.
// ---------------------------------------------------------------------------
__global__ __launch_bounds__(256) void maskbits_k(
    const int* __restrict__ mask, unsigned long long* __restrict__ bits, int nwords) {
  int gw   = (blockIdx.x * blockDim.x + threadIdx.x) >> 6;
  int lane = threadIdx.x & 63;
  int nw   = (gridDim.x * blockDim.x) >> 6;
  for (int w = gw; w < nwords; w += nw) {
    int m = mask[(size_t)w * 64 + lane];
    unsigned long long b = __ballot(m != 0);
    if (lane == 0) bits[w] = b;
  }
}

// ---------------------------------------------------------------------------
// W[1024][1024] f32 -> WT [n][k] bf16 (transposed, plain).
// ---------------------------------------------------------------------------
__global__ __launch_bounds__(256) void convT_k(
    const float* __restrict__ W, u16* __restrict__ T) {
  __shared__ float ts[64][68];
  const int t = threadIdx.x;
  const int r0 = blockIdx.y * 64, c0 = blockIdx.x * 64;
  const int rr = t >> 4, cc = t & 15;
#pragma unroll
  for (int p = 0; p < 4; ++p) {
    float4 v = *(const float4*)(W + (size_t)(r0 + rr + p*16) * DM + c0 + cc*4);
    *(float4*)&ts[rr + p*16][cc*4] = v;
  }
  __syncthreads();
  const int c = t >> 2, ch = t & 3;
  s16x8 h0, h1;
#pragma unroll
  for (int i = 0; i < 8; ++i) {
    h0[i] = (short)f2bf(ts[ch*16 + i][c]);
    h1[i] = (short)f2bf(ts[ch*16 + 8 + i][c]);
  }
  size_t base = (size_t)(c0 + c) * DM + r0 + ch*16;
  *(s16x8*)(T + base) = h0; *(s16x8*)(T + base + 8) = h1;
}

// ---------------------------------------------------------------------------
// bf16 MFMA GEMM: C[M,1024] = A[M,1024] @ W + bias.  A bf16 [M][1024],
// BT bf16 [n][k].  128x128 tile, BK=32, 4 waves (2x2), 4x4 frags/wave.
// Staging: global_load_lds dwordx4 (1KB/wave-op), LINEAR LDS [128][32].
// OUT_MODE: 0 = bf16 natural; 1 = bf16 transposed vT [b][h][dv][SLK];
//           2 = f32 natural.
// ---------------------------------------------------------------------------
template<int OUT_MODE>
__global__ __launch_bounds__(256) void gemm_bf16_k(
    const u16* __restrict__ Ab, const u16* __restrict__ BT,
    const float* __restrict__ bias, void* __restrict__ Out) {
  __shared__ u16 Ah[128 * 32];
  __shared__ u16 Bh[128 * 32];
  const int t = threadIdx.x;
  const int m0 = blockIdx.y * 128, n0 = blockIdx.x * 128;
  const int wid = t >> 6, lane = t & 63, lg = lane >> 4, lm = lane & 15;
  const int wr = wid >> 1, wc = wid & 1;
  f32x4 acc[4][4];
#pragma unroll
  for (int i = 0; i < 4; ++i)
#pragma unroll
    for (int j = 0; j < 4; ++j) acc[i][j] = (f32x4)(0.0f);

  const int c0 = wid * 2, c1 = wid * 2 + 1;
  const int sr0 = c0 * 16 + (lane >> 2), sr1 = c1 * 16 + (lane >> 2);
  const int spc = (lane & 3) * 8;
  for (int k0 = 0; k0 < DM; k0 += 32) {
    gl16(Ab + (size_t)(m0 + sr0) * DM + k0 + spc, &Ah[c0 * 512]);
    gl16(Ab + (size_t)(m0 + sr1) * DM + k0 + spc, &Ah[c1 * 512]);
    gl16(BT + (size_t)(n0 + sr0) * DM + k0 + spc, &Bh[c0 * 512]);
    gl16(BT + (size_t)(n0 + sr1) * DM + k0 + spc, &Bh[c1 * 512]);
    __syncthreads();
    s16x8 ah[4], bh[4];
#pragma unroll
    for (int i = 0; i < 4; ++i) {
      ah[i] = *(const s16x8*)&Ah[(wr*64 + i*16 + lm) * 32 + lg*8];
      bh[i] = *(const s16x8*)&Bh[(wc*64 + i*16 + lm) * 32 + lg*8];
    }
#pragma unroll
    for (int i = 0; i < 4; ++i)
#pragma unroll
      for (int j = 0; j < 4; ++j)
        acc[i][j] = __builtin_amdgcn_mfma_f32_16x16x32_bf16(ah[i], bh[j], acc[i][j], 0, 0, 0);
    __syncthreads();
  }
#pragma unroll
  for (int i = 0; i < 4; ++i)
#pragma unroll
    for (int j = 0; j < 4; ++j) {
      const int colg = n0 + wc*64 + j*16 + lm;
      const int rowb = m0 + wr*64 + i*16 + lg*4;
      const float bcol = bias[colg];
      if constexpr (OUT_MODE == 2) {
        float* O = (float*)Out;
#pragma unroll
        for (int r = 0; r < 4; ++r)
          O[(size_t)(rowb + r) * DM + colg] = acc[i][j][r] + bcol;
      } else if constexpr (OUT_MODE == 0) {
        u16* O = (u16*)Out;
#pragma unroll
        for (int r = 0; r < 4; ++r)
          O[(size_t)(rowb + r) * DM + colg] = f2bf(acc[i][j][r] + bcol);
      } else {  // vT transposed bf16
        u16* OT = (u16*)Out;
        const int bb = rowb >> 11, key = rowb & 2047;
        const int hh = colg >> 6, dv = colg & 63;
        s16x4 pk;
#pragma unroll
        for (int r = 0; r < 4; ++r) pk[r] = (short)f2bf(acc[i][j][r] + bcol);
        *(s16x4*)(OT + (((size_t)bb*NH + hh)*HD + dv)*SLK + key) = pk;
      }
    }
}

// ---------------------------------------------------------------------------
// Flash attention, MFMA, plain bf16. Block = (qt64, h, b), 4 waves.
// Deferred-max softmax; per-lane l partials, one final reduction.
// ---------------------------------------------------------------------------
__global__ __launch_bounds__(256) void attn_mfma_k(
    const u16* __restrict__ qb, const u16* __restrict__ kb,
    const u16* __restrict__ vT, const u32* __restrict__ mbits,
    u16* __restrict__ wv, float* __restrict__ ml) {
  __shared__ u16 ks[64][72];
  __shared__ u16 vs[64][72];
  __shared__ u16 ps[4][16][72];
  const int qt = blockIdx.x, h = blockIdx.y, b = blockIdx.z;
  const int t = threadIdx.x, wid = t >> 6, lane = t & 63, lg = lane >> 4, lm = lane & 15;
  const int q0 = qt * 64, qw = q0 + wid * 16;
  s16x8 qh[2];
#pragma unroll
  for (int s = 0; s < 2; ++s) {
    size_t off = ((size_t)(b*SLQ + qw + lm)) * DM + h*HD + s*32 + lg*8;
    qh[s] = *(const s16x8*)(qb + off);
  }
  f32x4 O[4];
#pragma unroll
  for (int j = 0; j < 4; ++j) O[j] = (f32x4)(0.0f);
  float m_r[4] = {-INFINITY, -INFINITY, -INFINITY, -INFINITY};
  float l_r[4] = {0.f, 0.f, 0.f, 0.f};   // per-lane partials (16 lanes/row)
  const int srow = t >> 2, sch = t & 3;
  for (int j0 = 0; j0 < SLK; j0 += 64) {
    {
      size_t koff = ((size_t)(b*SLK + j0 + srow)) * DM + h*HD + sch*16;
      *(s16x8*)&ks[srow][sch*16]     = *(const s16x8*)(kb + koff);
      *(s16x8*)&ks[srow][sch*16 + 8] = *(const s16x8*)(kb + koff + 8);
      size_t voff = (((size_t)b*NH + h)*HD + srow)*SLK + j0 + sch*16;
      *(s16x8*)&vs[srow][sch*16]     = *(const s16x8*)(vT + voff);
      *(s16x8*)&vs[srow][sch*16 + 8] = *(const s16x8*)(vT + voff + 8);
    }
    __syncthreads();
    // QK^T
    f32x4 sc[4];
#pragma unroll
    for (int j = 0; j < 4; ++j) {
      s16x8 kh0 = *(const s16x8*)&ks[j*16 + lm][lg*8];
      s16x8 kh1 = *(const s16x8*)&ks[j*16 + lm][32 + lg*8];
      f32x4 c = (f32x4)(0.0f);
      c = __builtin_amdgcn_mfma_f32_16x16x32_bf16(qh[0], kh0, c, 0, 0, 0);
      c = __builtin_amdgcn_mfma_f32_16x16x32_bf16(qh[1], kh1, c, 0, 0, 0);
      sc[j] = c;
    }
    // mask + deferred-max online softmax per q-row (reg r)
#pragma unroll
    for (int r = 0; r < 4; ++r) {
      size_t mrow = ((size_t)(b*SLQ + qw + lg*4 + r)) * (SLK/32) + (j0 >> 5);
      u32 w0 = mbits[mrow], w1 = mbits[mrow + 1];
      float sv[4];
#pragma unroll
      for (int j = 0; j < 4; ++j) {
        u32 w = (j < 2) ? w0 : w1;
        int bit = (w >> ((j*16 + lm) & 31)) & 1;
        sv[j] = bit ? sc[j][r] * 0.125f : -1e9f;
      }
      float pmax = fmaxf(fmaxf(sv[0], sv[1]), fmaxf(sv[2], sv[3]));
      if (!__all(pmax <= m_r[r] + 8.0f)) {       // slow path: ~tile 0 only
        float mx = pmax;
#pragma unroll
        for (int off = 1; off < 16; off <<= 1) mx = fmaxf(mx, __shfl_xor(mx, off, 64));
        float mnew  = fmaxf(m_r[r], mx);
        float alpha = __expf(m_r[r] - mnew);     // m=-inf -> alpha=0
        m_r[r] = mnew;
        l_r[r] *= alpha;
#pragma unroll
        for (int j = 0; j < 4; ++j) O[j][r] *= alpha;
      }
      float p0 = __expf(sv[0] - m_r[r]);
      float p1 = __expf(sv[1] - m_r[r]);
      float p2 = __expf(sv[2] - m_r[r]);
      float p3 = __expf(sv[3] - m_r[r]);
      l_r[r] += (p0 + p1) + (p2 + p3);
      ps[wid][lg*4 + r][0*16 + lm] = f2bf(p0);
      ps[wid][lg*4 + r][1*16 + lm] = f2bf(p1);
      ps[wid][lg*4 + r][2*16 + lm] = f2bf(p2);
      ps[wid][lg*4 + r][3*16 + lm] = f2bf(p3);
    }
    // PV
    {
      s16x8 pa0 = *(const s16x8*)&ps[wid][lm][lg*8];
      s16x8 pa1 = *(const s16x8*)&ps[wid][lm][32 + lg*8];
#pragma unroll
      for (int j = 0; j < 4; ++j) {
        s16x8 vb0 = *(const s16x8*)&vs[j*16 + lm][lg*8];
        s16x8 vb1 = *(const s16x8*)&vs[j*16 + lm][32 + lg*8];
        O[j] = __builtin_amdgcn_mfma_f32_16x16x32_bf16(pa0, vb0, O[j], 0, 0, 0);
        O[j] = __builtin_amdgcn_mfma_f32_16x16x32_bf16(pa1, vb1, O[j], 0, 0, 0);
      }
    }
    __syncthreads();
  }
  // final l reduction across the 16 lanes of each row (once)
#pragma unroll
  for (int r = 0; r < 4; ++r) {
#pragma unroll
    for (int off = 1; off < 16; off <<= 1) l_r[r] += __shfl_xor(l_r[r], off, 64);
  }
#pragma unroll
  for (int j = 0; j < 4; ++j)
#pragma unroll
    for (int r = 0; r < 4; ++r) {
      float v = O[j][r] / l_r[r];
      size_t row = (size_t)(b*SLQ + qw + lg*4 + r);
      wv[row*DM + h*HD + j*16 + lm] = f2bf(v);
    }
  if (lm == 0) {
#pragma unroll
    for (int r = 0; r < 4; ++r) {
      float* mp = ml + ((size_t)(b*NH + h)*SLQ + qw + lg*4 + r) * 2;
      mp[0] = m_r[r]; mp[1] = l_r[r];
    }
  }
}

// ---------------------------------------------------------------------------
// weight_mean v2: block = ONE (64q x 64k) tile; grid (SLK/64, SLQ/64, B)
// = 2048 blocks (8/CU -> latency hidden by TLP; was 512 = 2/CU).
// Loops all 16 heads in-block (cross-head sum without atomics).
// w = exp(s/8 - m)/l with attn's stored (m,l); masked -> 0; mean over h.
// ---------------------------------------------------------------------------
__global__ __launch_bounds__(256) void wmean_mfma_k(
    const u16* __restrict__ qb, const u16* __restrict__ kb,
    const u32* __restrict__ mbits, const float* __restrict__ ml,
    float* __restrict__ out1) {
  __shared__ u16 ks[64][72];
  const int t = threadIdx.x, wid = t >> 6, lane = t & 63, lg = lane >> 4, lm = lane & 15;
  const int j0 = blockIdx.x * 64, q0 = blockIdx.y * 64, b = blockIdx.z;
  const int qw = q0 + wid * 16;
  const int srow = t >> 2, sch = t & 3;
  f32x4 wm[4];
#pragma unroll
  for (int j = 0; j < 4; ++j) wm[j] = (f32x4)(0.0f);
  u32 w0[4], w1[4];
#pragma unroll
  for (int r = 0; r < 4; ++r) {
    size_t mrow = ((size_t)(b*SLQ + qw + lg*4 + r)) * (SLK/32) + (j0 >> 5);
    w0[r] = mbits[mrow]; w1[r] = mbits[mrow + 1];
  }
  for (int h = 0; h < NH; ++h) {
    __syncthreads();   // previous-h ks reads done
    {
      size_t koff = ((size_t)(b*SLK + j0 + srow)) * DM + h*HD + sch*16;
      *(s16x8*)&ks[srow][sch*16]     = *(const s16x8*)(kb + koff);
      *(s16x8*)&ks[srow][sch*16 + 8] = *(const s16x8*)(kb + koff + 8);
    }
    __syncthreads();
    s16x8 qh0, qh1;
    {
      size_t off = ((size_t)(b*SLQ + qw + lm)) * DM + h*HD + lg*8;
      qh0 = *(const s16x8*)(qb + off);
      qh1 = *(const s16x8*)(qb + off + 32);
    }
    float mr[4], li[4];
#pragma unroll
    for (int r = 0; r < 4; ++r) {
      const float* mp = ml + ((size_t)(b*NH + h)*SLQ + qw + lg*4 + r) * 2;
      mr[r] = mp[0]; li[r] = 1.0f / mp[1];
    }
#pragma unroll
    for (int j = 0; j < 4; ++j) {
      s16x8 kh0 = *(const s16x8*)&ks[j*16 + lm][lg*8];
      s16x8 kh1 = *(const s16x8*)&ks[j*16 + lm][32 + lg*8];
      f32x4 c = (f32x4)(0.0f);
      c = __builtin_amdgcn_mfma_f32_16x16x32_bf16(qh0, kh0, c, 0, 0, 0);
      c = __builtin_amdgcn_mfma_f32_16x16x32_bf16(qh1, kh1, c, 0, 0, 0);
#pragma unroll
      for (int r = 0; r < 4; ++r) {
        u32 w = (j < 2) ? w0[r] : w1[r];
        int bit = (w >> ((j*16 + lm) & 31)) & 1;
        float wvv = bit ? __expf(c[r] * 0.125f - mr[r]) * li[r] : 0.f;
        wm[j][r] += wvv;
      }
    }
  }
#pragma unroll
  for (int j = 0; j < 4; ++j)
#pragma unroll
    for (int r = 0; r < 4; ++r)
      out1[((size_t)b*SLQ + qw + lg*4 + r) * SLK + j0 + j*16 + lm]
          = wm[j][r] * (1.0f / NH);
}

// ---------------------------------------------------------------------------
extern "C" void kernel_launch(void* const* d_in, const int* in_sizes, int n_in,
                              void* d_out, int out_size, void* d_ws, size_t ws_size,
                              hipStream_t stream) {
  const float* mq    = (const float*)d_in[0];
  const float* reply = (const float*)d_in[1];
  const int*   maskp = (const int*)  d_in[2];
  const float* Wq = (const float*)d_in[3];
  const float* bq = (const float*)d_in[4];
  const float* Wk = (const float*)d_in[5];
  const float* bk = (const float*)d_in[6];
  const float* Wv = (const float*)d_in[7];
  const float* bv = (const float*)d_in[8];
  const float* Wo = (const float*)d_in[9];
  const float* bo = (const float*)d_in[10];

  float* out0 = (float*)d_out;
  float* out1 = out0 + (size_t)NB*SLQ*DM;

  // workspace carve -- total ~82 MB
  char* w = (char*)d_ws;
  auto carve = [&](size_t bytes) { char* p = w; w += bytes; return p; };
  u16* WqT = (u16*)carve((size_t)DM*DM*2);
  u16* WkT = (u16*)carve((size_t)DM*DM*2);
  u16* WvT = (u16*)carve((size_t)DM*DM*2);
  u16* WoT = (u16*)carve((size_t)DM*DM*2);
  u16* mqb = (u16*)carve((size_t)NB*SLQ*DM*2);
  u16* rpb = (u16*)carve((size_t)NB*SLK*DM*2);
  u16* qbf = (u16*)carve((size_t)NB*SLQ*DM*2);
  u16* kbf = (u16*)carve((size_t)NB*SLK*DM*2);
  u16* vT  = (u16*)carve((size_t)NB*SLK*DM*2);
  u16* wvb = (u16*)carve((size_t)NB*SLQ*DM*2);
  float* mlb = (float*)carve((size_t)NB*NH*SLQ*2*4);
  unsigned long long* mbits = (unsigned long long*)carve((size_t)NB*SLQ*SLK/8);

  cvt_bf16_k<<<512, 256, 0, stream>>>(mq,    mqb, NB*SLQ*DM);
  cvt_bf16_k<<<512, 256, 0, stream>>>(reply, rpb, NB*SLK*DM);
  maskbits_k<<<256, 256, 0, stream>>>(maskp, mbits, NB*SLQ*SLK/64);
  dim3 tg(16, 16);
  convT_k<<<tg, 256, 0, stream>>>(Wq, WqT);
  convT_k<<<tg, 256, 0, stream>>>(Wk, WkT);
  convT_k<<<tg, 256, 0, stream>>>(Wv, WvT);
  convT_k<<<tg, 256, 0, stream>>>(Wo, WoT);

  gemm_bf16_k<0><<<dim3(DM/128, (NB*SLQ)/128), 256, 0, stream>>>(mqb, WqT, bq, qbf);
  gemm_bf16_k<0><<<dim3(DM/128, (NB*SLK)/128), 256, 0, stream>>>(rpb, WkT, bk, kbf);
  gemm_bf16_k<1><<<dim3(DM/128, (NB*SLK)/128), 256, 0, stream>>>(rpb, WvT, bv, vT);

  attn_mfma_k<<<dim3(SLQ/64, NH, NB), 256, 0, stream>>>(
      qbf, kbf, vT, (const u32*)mbits, wvb, mlb);

  wmean_mfma_k<<<dim3(SLK/64, SLQ/64, NB), 256, 0, stream>>>(
      qbf, kbf, (const u32*)mbits, mlb, out1);

  gemm_bf16_k<2><<<dim3(DM/128, (NB*SLQ)/128), 256, 0, stream>>>(wvb, WoT, bo, out0);
}